// Round 11
// baseline (365.495 us; speedup 1.0000x reference)
//
#include <hip/hip_runtime.h>
#include <math.h>

#define N0 50000
#define N1 12500
#define N2 3125
#define NNZ 200000
#define NE0 800000
#define NE1 200000
#define NE2 50000
#define NT 65625           // N0+N1+N2
#define SEG_TOT 165625     // NT + 2*N0
#define EDGE_TOT 1050000   // NE0+NE1+NE2
#define ITEM_TOT 1450000   // EDGE_TOT + 2*NNZ
#define NBUCK 324          // ceil(SEG_TOT/512)
#define SPB 512            // segs per bucket
#define NBLK 355           // ceil(ITEM_TOT/4096)

typedef __attribute__((ext_vector_type(8))) short short8;
typedef __attribute__((ext_vector_type(8))) unsigned short ushort8;
typedef __attribute__((ext_vector_type(4))) float floatx4;

__device__ inline void split_bf16(float x, unsigned short& hi, unsigned short& lo) {
    unsigned xb = __float_as_uint(x);
    hi = (unsigned short)(xb >> 16);
    float hf = __uint_as_float((unsigned)hi << 16);
    lo = (unsigned short)(__float_as_uint(x - hf) >> 16);
}

// split 8 contiguous fp32 (LDS) into hi/lo bf16 frags
__device__ inline void split8(const float* p, short8& hi, short8& lo) {
    float4 u0 = *(const float4*)p;
    float4 u1 = *(const float4*)(p + 4);
    float f[8] = {u0.x, u0.y, u0.z, u0.w, u1.x, u1.y, u1.z, u1.w};
#pragma unroll
    for (int j = 0; j < 8; j++) {
        unsigned short h, l;
        split_bf16(f[j], h, l);
        hi[j] = (short)h; lo[j] = (short)l;
    }
}

// ================= binned CSR build =================
// seg space: [0,50000) L0 nodes, [50000,62500) L1, [62500,65625) L2,
// [65625,115625) interp1 rows, [115625,165625) interp2 rows.

__device__ inline int item_seg(int t, const int* __restrict__ ei0,
                               const int* __restrict__ ei1, const int* __restrict__ ei2,
                               const int* __restrict__ A1r, const int* __restrict__ A2r) {
    if (t < NE0) return ei0[NE0 + t];
    if (t < NE0 + NE1) return 50000 + ei1[NE1 + (t - NE0)];
    if (t < EDGE_TOT) return 62500 + ei2[NE2 + (t - (NE0 + NE1))];
    if (t < EDGE_TOT + NNZ) return NT + A1r[t - EDGE_TOT];
    return NT + N0 + A2r[t - (EDGE_TOT + NNZ)];
}

// A: per-block bucket histogram -> hist_g[bucket*NBLK + blk]
__global__ __launch_bounds__(256) void bin_hist(const int* __restrict__ ei0,
        const int* __restrict__ ei1, const int* __restrict__ ei2,
        const int* __restrict__ A1r, const int* __restrict__ A2r,
        int* __restrict__ hist_g) {
    __shared__ int h[NBUCK];
    for (int i = threadIdx.x; i < NBUCK; i += 256) h[i] = 0;
    __syncthreads();
    int base = blockIdx.x * 4096;
#pragma unroll
    for (int q = 0; q < 16; q++) {
        int t = base + q * 256 + threadIdx.x;
        if (t < ITEM_TOT) atomicAdd(&h[item_seg(t, ei0, ei1, ei2, A1r, A2r) >> 9], 1);
    }
    __syncthreads();
    for (int i = threadIdx.x; i < NBUCK; i += 256) hist_g[i * NBLK + blockIdx.x] = h[i];
}

// B1: bucket totals
__global__ void bucket_tot_k(const int* __restrict__ hist_g, int* __restrict__ btot) {
    int b = blockIdx.x;
    int s = 0;
    for (int i = threadIdx.x; i < NBLK; i += 64) s += hist_g[b * NBLK + i];
#pragma unroll
    for (int o = 32; o > 0; o >>= 1) s += __shfl_down(s, o, 64);
    if (threadIdx.x == 0) btot[b] = s;
}

// B3: per-bucket exclusive scan of hist_g row + bucket_base
__global__ void hist_scan(int* __restrict__ hist_g, const int* __restrict__ btot,
                          int* __restrict__ bbase) {
    int b = blockIdx.x, lane = threadIdx.x;
    int s = 0;
    for (int j = lane; j < b; j += 64) s += btot[j];
#pragma unroll
    for (int o = 32; o > 0; o >>= 1) s += __shfl_down(s, o, 64);
    int base = __shfl(s, 0, 64);
    if (lane == 0) {
        bbase[b] = base;
        if (b == NBUCK - 1) bbase[NBUCK] = ITEM_TOT;
    }
    int v[6], ts = 0;
#pragma unroll
    for (int q = 0; q < 6; q++) {
        int i = lane * 6 + q;
        v[q] = (i < NBLK) ? hist_g[b * NBLK + i] : 0;
        ts += v[q];
    }
    int sc = ts;
#pragma unroll
    for (int o = 1; o < 64; o <<= 1) {
        int t2 = __shfl_up(sc, o, 64);
        if (lane >= o) sc += t2;
    }
    int run = base + sc - ts;
#pragma unroll
    for (int q = 0; q < 6; q++) {
        int i = lane * 6 + q;
        if (i < NBLK) hist_g[b * NBLK + i] = run;
        run += v[q];
    }
}

// C: scatter items into bucket-ordered packed array
__global__ __launch_bounds__(256) void bin_scatter(const int* __restrict__ ei0,
        const int* __restrict__ ei1, const int* __restrict__ ei2,
        const int* __restrict__ A1r, const int* __restrict__ A1c, const float* __restrict__ A1v,
        const int* __restrict__ A2r, const int* __restrict__ A2c, const float* __restrict__ A2v,
        const int* __restrict__ hist_g, int* __restrict__ bpacked, float* __restrict__ bval) {
    __shared__ int cur[NBUCK];
    for (int i = threadIdx.x; i < NBUCK; i += 256) cur[i] = hist_g[i * NBLK + blockIdx.x];
    __syncthreads();
    int base = blockIdx.x * 4096;
#pragma unroll
    for (int q = 0; q < 16; q++) {
        int t = base + q * 256 + threadIdx.x;
        if (t >= ITEM_TOT) continue;
        int seg, pay;
        float val = 0.f;
        bool isv = false;
        if (t < NE0) { seg = ei0[NE0 + t]; pay = ei0[t]; }
        else if (t < NE0 + NE1) { int e = t - NE0; seg = 50000 + ei1[NE1 + e]; pay = ei1[e]; }
        else if (t < EDGE_TOT) { int e = t - (NE0 + NE1); seg = 62500 + ei2[NE2 + e]; pay = ei2[e]; }
        else if (t < EDGE_TOT + NNZ) { int k = t - EDGE_TOT; seg = NT + A1r[k]; pay = A1c[k]; val = A1v[k]; isv = true; }
        else { int k = t - (EDGE_TOT + NNZ); seg = NT + N0 + A2r[k]; pay = A2c[k]; val = A2v[k]; isv = true; }
        int bk = seg >> 9;
        int p = atomicAdd(&cur[bk], 1);
        bpacked[p] = ((seg - (bk << 9)) << 16) | pay;  // seg_local<512, pay<65536
        if (isv) bval[p] = val;
    }
}

// E: per-bucket count + scan + fill; writes offs[seg]=start directly.
__global__ __launch_bounds__(256) void bucket_fill(const int* __restrict__ bpacked,
        const float* __restrict__ bval, const int* __restrict__ bbase,
        int* __restrict__ offs, int* __restrict__ csrc, float* __restrict__ cval) {
    __shared__ int cnt[SPB];
    __shared__ int wsum2[4];
    int b = blockIdx.x, tid = threadIdx.x;
    int segbase = b * SPB;
    int seglim = SEG_TOT - segbase;
    if (seglim > SPB) seglim = SPB;
    int ibeg = bbase[b], iend = bbase[b + 1];
    for (int i = tid; i < SPB; i += 256) cnt[i] = 0;
    __syncthreads();
    for (int i = ibeg + tid; i < iend; i += 256)
        atomicAdd(&cnt[bpacked[i] >> 16], 1);
    __syncthreads();
    int lane = tid & 63, wid = tid >> 6;
    int v0 = cnt[tid * 2], v1 = cnt[tid * 2 + 1];
    int ts = v0 + v1, sc = ts;
#pragma unroll
    for (int o = 1; o < 64; o <<= 1) {
        int t2 = __shfl_up(sc, o, 64);
        if (lane >= o) sc += t2;
    }
    if (lane == 63) wsum2[wid] = sc;
    __syncthreads();
    int woff = 0;
    for (int w = 0; w < wid; w++) woff += wsum2[w];
    int ex = ibeg + woff + sc - ts;  // start position of seg tid*2
    __syncthreads();
    cnt[tid * 2] = ex;
    cnt[tid * 2 + 1] = ex + v0;
    if (tid * 2 < seglim) offs[segbase + tid * 2] = ex;
    if (tid * 2 + 1 < seglim) offs[segbase + tid * 2 + 1] = ex + v0;
    if (b == NBUCK - 1 && tid == 0) offs[SEG_TOT] = ITEM_TOT;
    __syncthreads();
    for (int i = ibeg + tid; i < iend; i += 256) {
        int w2 = bpacked[i];
        int sl = w2 >> 16, pay = w2 & 0xffff;
        int p = atomicAdd(&cnt[sl], 1);
        csrc[p] = pay;
        if (segbase + sl >= NT) cval[p - EDGE_TOT] = bval[i];
    }
}

// ================= batched gathers =================
// segment n spans [offs[n], offs[n+1])

__global__ void gather6_b(const float* __restrict__ x0, const float* __restrict__ x1,
                          const float* __restrict__ x2, const int* __restrict__ offs,
                          const int* __restrict__ csrc, float* __restrict__ agg6) {
    int n = blockIdx.x * blockDim.x + threadIdx.x;
    if (n >= NT) return;
    const float* x = (n < 50000) ? x0 : (n < 62500 ? x1 : x2);
    float a0 = 0, a1 = 0, a2 = 0, a3 = 0, a4 = 0, a5 = 0;
    int b = offs[n], e = offs[n + 1];
    for (int j = b; j < e; j++) {
        const float* p = x + (size_t)csrc[j] * 6;
        a0 += p[0]; a1 += p[1]; a2 += p[2]; a3 += p[3]; a4 += p[4]; a5 += p[5];
    }
    float* o = agg6 + (size_t)n * 6;
    o[0] = a0; o[1] = a1; o[2] = a2; o[3] = a3; o[4] = a4; o[5] = a5;
}

__device__ inline void acc_u4(uint4 u, float* a) {
    a[0] += __uint_as_float(u.x << 16);
    a[1] += __uint_as_float(u.x & 0xffff0000u);
    a[2] += __uint_as_float(u.y << 16);
    a[3] += __uint_as_float(u.y & 0xffff0000u);
    a[4] += __uint_as_float(u.z << 16);
    a[5] += __uint_as_float(u.z & 0xffff0000u);
    a[6] += __uint_as_float(u.w << 16);
    a[7] += __uint_as_float(u.w & 0xffff0000u);
}

__global__ __launch_bounds__(256) void interp_b(const float* __restrict__ ecat,
                                                const int* __restrict__ offs,
                                                const int* __restrict__ csrc,
                                                const float* __restrict__ cval,
                                                float* __restrict__ i1, float* __restrict__ i2) {
    int t = blockIdx.x * blockDim.x + threadIdx.x;
    int ng = t / 24, g = t % 24;
    if (ng >= 2 * N0) return;
    int a = (ng >= N0) ? 1 : 0;
    int nl = ng - a * N0;
    const float* e = ecat + (size_t)(a ? 62500 : 50000) * 96;
    float* ob = a ? i2 : i1;
    int seg = NT + ng;
    float4 s = {0.f, 0.f, 0.f, 0.f};
    int b = offs[seg], en = offs[seg + 1];
    for (int j = b; j < en; j++) {
        int c = csrc[j];
        float v = cval[j - EDGE_TOT];
        float4 w = ((const float4*)(e + (size_t)c * 96))[g];
        s.x += v * w.x; s.y += v * w.y; s.z += v * w.z; s.w += v * w.w;
    }
    ((float4*)(ob + (size_t)nl * 96))[g] = s;
}

// ================= weight preconvert =================
__global__ void conv_weights(const float* __restrict__ c2Wrel, const float* __restrict__ c2Wroot,
                             const float* __restrict__ linW, const float* __restrict__ dW0,
                             unsigned short* __restrict__ c2hi, unsigned short* __restrict__ c2lo,
                             unsigned short* __restrict__ lhi, unsigned short* __restrict__ llo,
                             float* __restrict__ decWt) {
    int t = blockIdx.x * blockDim.x + threadIdx.x;
    if (t < 98304) {
        int i = t / 32768, r = t % 32768;
        int n = r / 256, k = r % 256;
        float w = (k < 128) ? c2Wrel[i * 16384 + k * 128 + n]
                            : c2Wroot[i * 16384 + (k - 128) * 128 + n];
        unsigned short hi, lo;
        split_bf16(w, hi, lo);
        c2hi[t] = hi; c2lo[t] = lo;
    } else if (t < 135168) {
        int u = t - 98304;
        int i = u / 12288, r = u % 12288;
        int n = r / 128, k = r % 128;
        unsigned short hi, lo;
        split_bf16(linW[i * 12288 + k * 96 + n], hi, lo);
        lhi[u] = hi; llo[u] = lo;
    } else if (t < 153600) {
        int u = t - 135168;
        int chn = u / 6144, r = u % 6144;
        int col = r / 96, k = r % 96;
        decWt[u] = dW0[chn * 6144 + k * 64 + col];
    }
}

// ================= conv1 (fp32, K=12) -> writes h1 as node-major bf16 planes
__global__ __launch_bounds__(256) void conv1_b(
        const float* __restrict__ agg6, const float* __restrict__ x0,
        const float* __restrict__ x1, const float* __restrict__ x2,
        const float* __restrict__ Wrel, const float* __restrict__ Wroot,
        const float* __restrict__ brel,
        unsigned short* __restrict__ h1hi, unsigned short* __restrict__ h1lo) {
    __shared__ float As[16][65];
    __shared__ float Ws[16][64];
    int bx = blockIdx.x;
    int l, lbk;
    if (bx < 782) { l = 0; lbk = bx; }
    else if (bx < 978) { l = 1; lbk = bx - 782; }
    else { l = 2; lbk = bx - 978; }
    int nb = (l == 0) ? 0 : (l == 1 ? 50000 : 62500);
    int M = (l == 0) ? N0 : (l == 1 ? N1 : N2);
    const float* xl = (l == 0) ? x0 : (l == 1 ? x1 : x2);
    const float* A1 = agg6 + (size_t)nb * 6;
    const float* W1 = Wrel + l * 768;
    const float* W2 = Wroot + l * 768;
    const float* bias = brel + l * 128;
    int m0 = lbk * 64, n0 = blockIdx.y * 64;
    int tid = threadIdx.x;
    int tm = tid >> 4, tn = tid & 15;
    float acc[4][4] = {};
#pragma unroll
    for (int q = 0; q < 4; q++) {
        int idx = tid + q * 256;
        int row = idx >> 4, kk = idx & 15;
        int m = m0 + row;
        float v = 0.f;
        if (m < M && kk < 12)
            v = (kk < 6) ? A1[(size_t)m * 6 + kk] : xl[(size_t)m * 6 + kk - 6];
        As[kk][row] = v;
    }
#pragma unroll
    for (int q = 0; q < 4; q++) {
        int idx = tid + q * 256;
        int kk = idx >> 6, nn2 = idx & 63;
        float v = 0.f;
        if (kk < 12)
            v = (kk < 6) ? W1[kk * 128 + n0 + nn2] : W2[(kk - 6) * 128 + n0 + nn2];
        Ws[kk][nn2] = v;
    }
    __syncthreads();
#pragma unroll
    for (int k = 0; k < 12; k++) {
        float av[4], wv[4];
#pragma unroll
        for (int i = 0; i < 4; i++) av[i] = As[k][tm * 4 + i];
#pragma unroll
        for (int j = 0; j < 4; j++) wv[j] = Ws[k][tn * 4 + j];
#pragma unroll
        for (int i = 0; i < 4; i++)
#pragma unroll
            for (int j = 0; j < 4; j++) acc[i][j] += av[i] * wv[j];
    }
#pragma unroll
    for (int i = 0; i < 4; i++) {
        int m = m0 + tm * 4 + i;
        if (m >= M) continue;
        unsigned short hs[4], ls[4];
#pragma unroll
        for (int j = 0; j < 4; j++) {
            float v = fmaxf(acc[i][j] + bias[n0 + tn * 4 + j], 0.f);
            split_bf16(v, hs[j], ls[j]);
        }
        uint2 ph = {(unsigned)hs[0] | ((unsigned)hs[1] << 16),
                    (unsigned)hs[2] | ((unsigned)hs[3] << 16)};
        uint2 pl = {(unsigned)ls[0] | ((unsigned)ls[1] << 16),
                    (unsigned)ls[2] | ((unsigned)ls[3] << 16)};
        size_t off = (size_t)(nb + m) * 128 + n0 + tn * 4;
        *(uint2*)(h1hi + off) = ph;
        *(uint2*)(h1lo + off) = pl;
    }
}

// ================= fused gather + conv2 + lin (split-bf16 MFMA) =================
// Gathers the block's 64-row agg tile from h1hi (CSR) into LDS fp32, then
// phase1: h2 = relu([agg|h1] @ W2 + b2)  (K=256, J=128) -> LDS hi/lo
// phase2: e = h2 @ linW + linb           (K=128, J=96)
__global__ __launch_bounds__(256) void conv2lin(
        const unsigned short* __restrict__ h1hi, const unsigned short* __restrict__ h1lo,
        const int* __restrict__ offs, const int* __restrict__ csrc,
        const unsigned short* __restrict__ c2hi, const unsigned short* __restrict__ c2lo,
        const float* __restrict__ c2b,
        const unsigned short* __restrict__ lnhi, const unsigned short* __restrict__ lnlo,
        const float* __restrict__ lnb, float* __restrict__ ecat) {
    __shared__ unsigned short smem[32256];  // 64.5 KB union
    float* aggT = (float*)smem;             // 64 x 132 fp32 (pitch 132) = 16896 ush
    unsigned short* Ah = smem + 16896;      // 64*40
    unsigned short* Al = smem + 19456;
    unsigned short* Bh = smem + 22016;      // 128*40
    unsigned short* Bl = smem + 27136;      // end 32256
    unsigned short* Hh = smem;              // phase 2: 64*136 (overlays aggT/Ah - dead)
    unsigned short* Hl = smem + 8704;
    unsigned short* B2h = smem + 17408;     // 96*40 (overlays Ah/Al/Bh - dead)
    unsigned short* B2l = smem + 21248;     // end 25088
    const int LDA = 40;

    int bx = blockIdx.x;
    int l, lbk;
    if (bx < 782) { l = 0; lbk = bx; }
    else if (bx < 978) { l = 1; lbk = bx - 782; }
    else { l = 2; lbk = bx - 978; }
    int nb = (l == 0) ? 0 : (l == 1 ? 50000 : 62500);
    int M = (l == 0) ? N0 : (l == 1 ? N1 : N2);
    const unsigned short* A2h = h1hi + (size_t)nb * 128;
    const unsigned short* A2l = h1lo + (size_t)nb * 128;
    const unsigned short* W1h = c2hi + l * 32768;
    const unsigned short* W1l = c2lo + l * 32768;
    const float* b1 = c2b + l * 128;
    const unsigned short* W2h = lnhi + l * 12288;
    const unsigned short* W2l = lnlo + l * 12288;
    const float* b2 = lnb + l * 96;
    float* C = ecat + (size_t)nb * 96;
    int m0 = lbk * 64;

    int tid = threadIdx.x;
    int lane = tid & 63, wid = tid >> 6;
    int waveM = wid & 1, waveN = wid >> 1;
    int l15 = lane & 15, quad = lane >> 4;
    int arow = tid >> 2, acol = (tid & 3) * 8;
    int brow = tid >> 1, bcol = (tid & 1) * 16;

    // ---- fused gather: aggT[node][0..127] = sum_{edges} bf16(h1hi[src]) ----
#pragma unroll
    for (int it = 0; it < 4; it++) {
        int slot = it * 256 + tid;
        int node = slot >> 4, q = slot & 15;
        int m = m0 + node;
        float a[8] = {};
        if (m < M) {
            int seg = nb + m;
            int jb = offs[seg], je = offs[seg + 1];
            int j = jb;
            for (; j + 1 < je; j += 2) {
                int s0 = csrc[j], s1 = csrc[j + 1];
                uint4 u0 = *(const uint4*)(A2h + (size_t)s0 * 128 + q * 8);
                uint4 u1 = *(const uint4*)(A2h + (size_t)s1 * 128 + q * 8);
                acc_u4(u0, a);
                acc_u4(u1, a);
            }
            if (j < je) {
                uint4 u0 = *(const uint4*)(A2h + (size_t)csrc[j] * 128 + q * 8);
                acc_u4(u0, a);
            }
        }
        float* o = aggT + node * 132 + q * 8;
        *(float4*)o = (float4){a[0], a[1], a[2], a[3]};
        *(float4*)(o + 4) = (float4){a[4], a[5], a[6], a[7]};
    }

    floatx4 acc[2][4];
#pragma unroll
    for (int i = 0; i < 2; i++)
#pragma unroll
        for (int j = 0; j < 4; j++) acc[i][j] = (floatx4){0.f, 0.f, 0.f, 0.f};

    // ---- phase 1: K=256 ----
    for (int kt = 0; kt < 256; kt += 32) {
        __syncthreads();   // first iter: gather->read; later: mfma->overwrite
        {
            int m = m0 + arow;
            ushort8 hv, lv;
            int kg = kt + acol;
            if (kg < 128) {  // uniform per kt: read gathered LDS tile
                const float* src = aggT + arow * 132 + kg;
                float4 u0 = *(const float4*)src;
                float4 u1 = *(const float4*)(src + 4);
                float xv[8] = {u0.x, u0.y, u0.z, u0.w, u1.x, u1.y, u1.z, u1.w};
#pragma unroll
                for (int q = 0; q < 8; q++) {
                    unsigned short h, lo2;
                    split_bf16(xv[q], h, lo2);
                    hv[q] = h; lv[q] = lo2;
                }
            } else if (m < M) {
                size_t off = (size_t)m * 128 + (kg - 128);
                hv = *(const ushort8*)(A2h + off);
                lv = *(const ushort8*)(A2l + off);
            } else {
                hv = (ushort8)0; lv = (ushort8)0;
            }
            *(ushort8*)(&Ah[arow * LDA + acol]) = hv;
            *(ushort8*)(&Al[arow * LDA + acol]) = lv;
        }
        {
            const unsigned short* ph = W1h + (size_t)brow * 256 + kt + bcol;
            const unsigned short* pl = W1l + (size_t)brow * 256 + kt + bcol;
            *(ushort8*)(&Bh[brow * LDA + bcol]) = *(const ushort8*)ph;
            *(ushort8*)(&Bh[brow * LDA + bcol + 8]) = *(const ushort8*)(ph + 8);
            *(ushort8*)(&Bl[brow * LDA + bcol]) = *(const ushort8*)pl;
            *(ushort8*)(&Bl[brow * LDA + bcol + 8]) = *(const ushort8*)(pl + 8);
        }
        __syncthreads();
        short8 af[2][2];
#pragma unroll
        for (int mt = 0; mt < 2; mt++) {
            int r = waveM * 32 + mt * 16 + l15;
            af[mt][0] = *(const short8*)(&Ah[r * LDA + quad * 8]);
            af[mt][1] = *(const short8*)(&Al[r * LDA + quad * 8]);
        }
#pragma unroll
        for (int nt = 0; nt < 4; nt++) {
            int c = waveN * 64 + nt * 16 + l15;
            short8 bh = *(const short8*)(&Bh[c * LDA + quad * 8]);
            short8 bl = *(const short8*)(&Bl[c * LDA + quad * 8]);
#pragma unroll
            for (int mt = 0; mt < 2; mt++) {
                acc[mt][nt] = __builtin_amdgcn_mfma_f32_16x16x32_bf16(af[mt][0], bh, acc[mt][nt], 0, 0, 0);
                acc[mt][nt] = __builtin_amdgcn_mfma_f32_16x16x32_bf16(af[mt][0], bl, acc[mt][nt], 0, 0, 0);
                acc[mt][nt] = __builtin_amdgcn_mfma_f32_16x16x32_bf16(af[mt][1], bh, acc[mt][nt], 0, 0, 0);
            }
        }
    }

    // ---- transition: h2 tile -> LDS hi/lo ----
    __syncthreads();
    {
        float bs1[4];
#pragma unroll
        for (int nt = 0; nt < 4; nt++) bs1[nt] = b1[waveN * 64 + nt * 16 + l15];
#pragma unroll
        for (int mt = 0; mt < 2; mt++)
#pragma unroll
            for (int nt = 0; nt < 4; nt++)
#pragma unroll
                for (int r = 0; r < 4; r++) {
                    int row = waveM * 32 + mt * 16 + quad * 4 + r;
                    int col = waveN * 64 + nt * 16 + l15;
                    float v = fmaxf(acc[mt][nt][r] + bs1[nt], 0.f);
                    unsigned short h, lo2;
                    split_bf16(v, h, lo2);
                    Hh[row * 136 + col] = h;
                    Hl[row * 136 + col] = lo2;
                }
    }

    // ---- phase 2: K=128, J=96 ----
    floatx4 acc2[2][3];
#pragma unroll
    for (int i = 0; i < 2; i++)
#pragma unroll
        for (int j = 0; j < 3; j++) acc2[i][j] = (floatx4){0.f, 0.f, 0.f, 0.f};

    for (int kt = 0; kt < 128; kt += 32) {
        __syncthreads();
        if (brow < 96) {
            const unsigned short* ph = W2h + (size_t)brow * 128 + kt + bcol;
            const unsigned short* pl = W2l + (size_t)brow * 128 + kt + bcol;
            *(ushort8*)(&B2h[brow * LDA + bcol]) = *(const ushort8*)ph;
            *(ushort8*)(&B2h[brow * LDA + bcol + 8]) = *(const ushort8*)(ph + 8);
            *(ushort8*)(&B2l[brow * LDA + bcol]) = *(const ushort8*)pl;
            *(ushort8*)(&B2l[brow * LDA + bcol + 8]) = *(const ushort8*)(pl + 8);
        }
        __syncthreads();
        short8 af2[2][2];
#pragma unroll
        for (int mt = 0; mt < 2; mt++) {
            int r = waveM * 32 + mt * 16 + l15;
            af2[mt][0] = *(const short8*)(&Hh[r * 136 + kt + quad * 8]);
            af2[mt][1] = *(const short8*)(&Hl[r * 136 + kt + quad * 8]);
        }
#pragma unroll
        for (int nt = 0; nt < 3; nt++) {
            int c = waveN * 48 + nt * 16 + l15;
            short8 bh = *(const short8*)(&B2h[c * LDA + quad * 8]);
            short8 bl = *(const short8*)(&B2l[c * LDA + quad * 8]);
#pragma unroll
            for (int mt = 0; mt < 2; mt++) {
                acc2[mt][nt] = __builtin_amdgcn_mfma_f32_16x16x32_bf16(af2[mt][0], bh, acc2[mt][nt], 0, 0, 0);
                acc2[mt][nt] = __builtin_amdgcn_mfma_f32_16x16x32_bf16(af2[mt][0], bl, acc2[mt][nt], 0, 0, 0);
                acc2[mt][nt] = __builtin_amdgcn_mfma_f32_16x16x32_bf16(af2[mt][1], bh, acc2[mt][nt], 0, 0, 0);
            }
        }
    }

    // ---- epilogue ----
    float bs2[3];
#pragma unroll
    for (int nt = 0; nt < 3; nt++) bs2[nt] = b2[waveN * 48 + nt * 16 + l15];
#pragma unroll
    for (int mt = 0; mt < 2; mt++)
#pragma unroll
        for (int r = 0; r < 4; r++) {
            int grow = m0 + waveM * 32 + mt * 16 + quad * 4 + r;
            if (grow >= M) continue;
#pragma unroll
            for (int nt = 0; nt < 3; nt++) {
                int col = waveN * 48 + nt * 16 + l15;
                C[(size_t)grow * 96 + col] = acc2[mt][nt][r] + bs2[nt];
            }
        }
}

// ================= MFMA decoder =================
__global__ __launch_bounds__(256) void decoder_mfma(
        const float* __restrict__ e0, const float* __restrict__ i1,
        const float* __restrict__ i2, const float* __restrict__ decWt,
        const float* __restrict__ b0, const float* __restrict__ Wout,
        const float* __restrict__ bout, float* __restrict__ out, int N) {
    __shared__ float As[6400];   // [row][k], pitch 100
    __shared__ float Bs[6400];   // [col][k], pitch 100
    __shared__ float red[64][2];
    __shared__ float sb0[64], sWo[64];
    int ch = blockIdx.y;
    int tid = threadIdx.x;
    int m0 = blockIdx.x * 64;

    for (int idx = tid; idx < 1536; idx += 256) {
        int col = idx / 24, k0 = (idx % 24) * 4;
        *(float4*)(&Bs[col * 100 + k0]) = *(const float4*)(decWt + ch * 6144 + col * 96 + k0);
    }
    if (tid < 64) { sb0[tid] = b0[ch * 64 + tid]; sWo[tid] = Wout[ch * 64 + tid]; }
    for (int idx = tid; idx < 1536; idx += 256) {
        int row = idx / 24, k0 = (idx % 24) * 4;
        int m = m0 + row;
        float4 v = {0.f, 0.f, 0.f, 0.f};
        if (m < N) {
            const float* base = (k0 < 32) ? e0 : (k0 < 64 ? i1 : i2);
            v = *(const float4*)(base + (size_t)m * 96 + ch * 32 + (k0 & 31));
        }
        *(float4*)(&As[row * 100 + k0]) = v;
    }
    __syncthreads();

    int lane = tid & 63, wid = tid >> 6;
    int waveM = wid & 1, waveN = wid >> 1;
    int l15 = lane & 15, quad = lane >> 4;
    floatx4 acc[2][2];
#pragma unroll
    for (int i = 0; i < 2; i++)
#pragma unroll
        for (int j = 0; j < 2; j++) acc[i][j] = (floatx4){0.f, 0.f, 0.f, 0.f};

#pragma unroll
    for (int kt = 0; kt < 96; kt += 32) {
        short8 ah[2], al[2];
#pragma unroll
        for (int mt = 0; mt < 2; mt++) {
            int r = waveM * 32 + mt * 16 + l15;
            split8(&As[r * 100 + kt + quad * 8], ah[mt], al[mt]);
        }
#pragma unroll
        for (int nt = 0; nt < 2; nt++) {
            int c = waveN * 32 + nt * 16 + l15;
            short8 bh, bl;
            split8(&Bs[c * 100 + kt + quad * 8], bh, bl);
#pragma unroll
            for (int mt = 0; mt < 2; mt++) {
                acc[mt][nt] = __builtin_amdgcn_mfma_f32_16x16x32_bf16(ah[mt], bh, acc[mt][nt], 0, 0, 0);
                acc[mt][nt] = __builtin_amdgcn_mfma_f32_16x16x32_bf16(ah[mt], bl, acc[mt][nt], 0, 0, 0);
                acc[mt][nt] = __builtin_amdgcn_mfma_f32_16x16x32_bf16(al[mt], bh, acc[mt][nt], 0, 0, 0);
            }
        }
    }

    float cb0[2], cwo[2];
#pragma unroll
    for (int nt = 0; nt < 2; nt++) {
        int col = waveN * 32 + nt * 16 + l15;
        cb0[nt] = sb0[col]; cwo[nt] = sWo[col];
    }
    float p[2][4];
#pragma unroll
    for (int mt = 0; mt < 2; mt++)
#pragma unroll
        for (int r = 0; r < 4; r++) {
            float s = 0.f;
#pragma unroll
            for (int nt = 0; nt < 2; nt++) {
                float h = acc[mt][nt][r] + cb0[nt];
                h = h > 0.f ? h : (expf(h) - 1.0f);
                s += h * cwo[nt];
            }
            p[mt][r] = s;
        }
#pragma unroll
    for (int mt = 0; mt < 2; mt++)
#pragma unroll
        for (int r = 0; r < 4; r++) {
#pragma unroll
            for (int msk = 1; msk < 16; msk <<= 1)
                p[mt][r] += __shfl_xor(p[mt][r], msk, 64);
        }
    if (l15 == 0) {
#pragma unroll
        for (int mt = 0; mt < 2; mt++)
#pragma unroll
            for (int r = 0; r < 4; r++) {
                int row = waveM * 32 + mt * 16 + quad * 4 + r;
                red[row][waveN] = p[mt][r];
            }
    }
    __syncthreads();
    if (tid < 64) {
        int m = m0 + tid;
        if (m < N) out[(size_t)m * 3 + ch] = red[tid][0] + red[tid][1] + bout[ch];
    }
}

// ================= host launch =================

extern "C" void kernel_launch(void* const* d_in, const int* in_sizes, int n_in,
                              void* d_out, int out_size, void* d_ws, size_t ws_size,
                              hipStream_t stream) {
    const float* x0 = (const float*)d_in[0];
    const float* x1 = (const float*)d_in[1];
    const float* x2 = (const float*)d_in[2];
    const int* ei0 = (const int*)d_in[3];
    const int* ei1 = (const int*)d_in[4];
    const int* ei2 = (const int*)d_in[5];
    const int* A1r = (const int*)d_in[6];
    const int* A1c = (const int*)d_in[7];
    const float* A1v = (const float*)d_in[8];
    const int* A2r = (const int*)d_in[9];
    const int* A2c = (const int*)d_in[10];
    const float* A2v = (const float*)d_in[11];
    const float* c1Wrel = (const float*)d_in[12];
    const float* c1brel = (const float*)d_in[13];
    const float* c1Wroot = (const float*)d_in[14];
    const float* c2Wrel = (const float*)d_in[15];
    const float* c2brel = (const float*)d_in[16];
    const float* c2Wroot = (const float*)d_in[17];
    const float* linW = (const float*)d_in[18];
    const float* linb = (const float*)d_in[19];
    const float* dW0 = (const float*)d_in[20];
    const float* db0 = (const float*)d_in[21];
    const float* dWout = (const float*)d_in[22];
    const float* dbout = (const float*)d_in[23];
    float* out = (float*)d_out;

    // ---- workspace (float words) ----
    float* ws = (float*)d_ws;
    float* agg6 = ws;                            // [0, 400,000)
    unsigned short* h1hi = (unsigned short*)(ws + 400000);   // node-major, 8.4M ushorts
    unsigned short* h1lo = (unsigned short*)(ws + 4600000);  // node-major, 8.4M ushorts
    float* ecat = ws + 17200000;                 // 6.3M words
    // binned intermediates live at [8.8M, 17.2M) (dead after bucket_fill)
    int* bpacked = (int*)(ws + 8800000);         // 1,450,000
    float* bval = ws + 8800000 + 1450000;        // 1,450,000
    float* i1 = ws + 8800000;                    // written by interp_b (after conv2lin)
    float* i2 = ws + 400000;                     // overlays h1 planes (dead after conv2lin)
    int* hist_g = (int*)(ws + 23500000);         // NBUCK*NBLK = 115,020
    int* btot = (int*)(ws + 23615020);           // 324
    int* bbase = (int*)(ws + 23615344);          // 325
    int* offs = (int*)(ws + 23665632);           // 165,626
    int* csrc = (int*)(ws + 23831264);           // 1,450,000
    float* cval = ws + 25281392;                 // 400,000
    unsigned short* c2hi = (unsigned short*)(ws + 25681392); // 98,304 ushort
    unsigned short* c2lo = c2hi + 98304;
    unsigned short* lnhi = c2lo + 98304;                     // 36,864 ushort
    unsigned short* lnlo = lnhi + 36864;
    float* decWt = ws + 25681392 + 135168;       // 18,432 floats; ends ~25,834,992 (~103.3 MB)

    conv_weights<<<(153600 + 255) / 256, 256, 0, stream>>>(
        c2Wrel, c2Wroot, linW, dW0, c2hi, c2lo, lnhi, lnlo, decWt);

    // ---- binned CSR build ----
    bin_hist<<<NBLK, 256, 0, stream>>>(ei0, ei1, ei2, A1r, A2r, hist_g);
    bucket_tot_k<<<NBUCK, 64, 0, stream>>>(hist_g, btot);
    hist_scan<<<NBUCK, 64, 0, stream>>>(hist_g, btot, bbase);
    bin_scatter<<<NBLK, 256, 0, stream>>>(ei0, ei1, ei2, A1r, A1c, A1v,
                                          A2r, A2c, A2v, hist_g, bpacked, bval);
    bucket_fill<<<NBUCK, 256, 0, stream>>>(bpacked, bval, bbase, offs, csrc, cval);

    // ---- encoder ----
    gather6_b<<<(NT + 255) / 256, 256, 0, stream>>>(x0, x1, x2, offs, csrc, agg6);
    dim3 g1(1027, 2);
    conv1_b<<<g1, 256, 0, stream>>>(agg6, x0, x1, x2, c1Wrel, c1Wroot, c1brel, h1hi, h1lo);
    conv2lin<<<1027, 256, 0, stream>>>(h1hi, h1lo, offs, csrc, c2hi, c2lo, c2brel,
                                       lnhi, lnlo, linb, ecat);

    // ---- interpolation (i1 over dead bpacked region, i2 over dead h1 planes) ----
    interp_b<<<((size_t)2 * N0 * 24 + 255) / 256, 256, 0, stream>>>(
        ecat, offs, csrc, cval, i1, i2);

    // ---- decoder ----
    dim3 gd(782, 3);
    decoder_mfma<<<gd, 256, 0, stream>>>(ecat, i1, i2, decWt, db0, dWout, dbout, out, N0);
}

// Round 12
// 309.454 us; speedup vs baseline: 1.1811x; 1.1811x over previous
//
#include <hip/hip_runtime.h>
#include <math.h>

#define N0 50000
#define N1 12500
#define N2 3125
#define NNZ 200000
#define NE0 800000
#define NE1 200000
#define NE2 50000
#define NT 65625           // N0+N1+N2
#define SEG_TOT 165625     // NT + 2*N0
#define EDGE_TOT 1050000   // NE0+NE1+NE2
#define ITEM_TOT 1450000   // EDGE_TOT + 2*NNZ
#define NBUCK 324          // ceil(SEG_TOT/512)
#define SPB 512            // segs per bucket
#define NBLK 355           // ceil(ITEM_TOT/4096)

typedef __attribute__((ext_vector_type(8))) short short8;
typedef __attribute__((ext_vector_type(8))) unsigned short ushort8;
typedef __attribute__((ext_vector_type(4))) float floatx4;

__device__ inline void split_bf16(float x, unsigned short& hi, unsigned short& lo) {
    unsigned xb = __float_as_uint(x);
    hi = (unsigned short)(xb >> 16);
    float hf = __uint_as_float((unsigned)hi << 16);
    lo = (unsigned short)(__float_as_uint(x - hf) >> 16);
}

// split 8 contiguous fp32 (LDS) into hi/lo bf16 frags
__device__ inline void split8(const float* p, short8& hi, short8& lo) {
    float4 u0 = *(const float4*)p;
    float4 u1 = *(const float4*)(p + 4);
    float f[8] = {u0.x, u0.y, u0.z, u0.w, u1.x, u1.y, u1.z, u1.w};
#pragma unroll
    for (int j = 0; j < 8; j++) {
        unsigned short h, l;
        split_bf16(f[j], h, l);
        hi[j] = (short)h; lo[j] = (short)l;
    }
}

// ================= binned CSR build =================
// seg space: [0,50000) L0 nodes, [50000,62500) L1, [62500,65625) L2,
// [65625,115625) interp1 rows, [115625,165625) interp2 rows.

__device__ inline int item_seg(int t, const int* __restrict__ ei0,
                               const int* __restrict__ ei1, const int* __restrict__ ei2,
                               const int* __restrict__ A1r, const int* __restrict__ A2r) {
    if (t < NE0) return ei0[NE0 + t];
    if (t < NE0 + NE1) return 50000 + ei1[NE1 + (t - NE0)];
    if (t < EDGE_TOT) return 62500 + ei2[NE2 + (t - (NE0 + NE1))];
    if (t < EDGE_TOT + NNZ) return NT + A1r[t - EDGE_TOT];
    return NT + N0 + A2r[t - (EDGE_TOT + NNZ)];
}

// A: per-block bucket histogram -> hist_g[bucket*NBLK + blk]
__global__ __launch_bounds__(256) void bin_hist(const int* __restrict__ ei0,
        const int* __restrict__ ei1, const int* __restrict__ ei2,
        const int* __restrict__ A1r, const int* __restrict__ A2r,
        int* __restrict__ hist_g) {
    __shared__ int h[NBUCK];
    for (int i = threadIdx.x; i < NBUCK; i += 256) h[i] = 0;
    __syncthreads();
    int base = blockIdx.x * 4096;
#pragma unroll
    for (int q = 0; q < 16; q++) {
        int t = base + q * 256 + threadIdx.x;
        if (t < ITEM_TOT) atomicAdd(&h[item_seg(t, ei0, ei1, ei2, A1r, A2r) >> 9], 1);
    }
    __syncthreads();
    for (int i = threadIdx.x; i < NBUCK; i += 256) hist_g[i * NBLK + blockIdx.x] = h[i];
}

// B1: bucket totals
__global__ void bucket_tot_k(const int* __restrict__ hist_g, int* __restrict__ btot) {
    int b = blockIdx.x;
    int s = 0;
    for (int i = threadIdx.x; i < NBLK; i += 64) s += hist_g[b * NBLK + i];
#pragma unroll
    for (int o = 32; o > 0; o >>= 1) s += __shfl_down(s, o, 64);
    if (threadIdx.x == 0) btot[b] = s;
}

// B3: per-bucket exclusive scan of hist_g row + bucket_base
__global__ void hist_scan(int* __restrict__ hist_g, const int* __restrict__ btot,
                          int* __restrict__ bbase) {
    int b = blockIdx.x, lane = threadIdx.x;
    int s = 0;
    for (int j = lane; j < b; j += 64) s += btot[j];
#pragma unroll
    for (int o = 32; o > 0; o >>= 1) s += __shfl_down(s, o, 64);
    int base = __shfl(s, 0, 64);
    if (lane == 0) {
        bbase[b] = base;
        if (b == NBUCK - 1) bbase[NBUCK] = ITEM_TOT;
    }
    int v[6], ts = 0;
#pragma unroll
    for (int q = 0; q < 6; q++) {
        int i = lane * 6 + q;
        v[q] = (i < NBLK) ? hist_g[b * NBLK + i] : 0;
        ts += v[q];
    }
    int sc = ts;
#pragma unroll
    for (int o = 1; o < 64; o <<= 1) {
        int t2 = __shfl_up(sc, o, 64);
        if (lane >= o) sc += t2;
    }
    int run = base + sc - ts;
#pragma unroll
    for (int q = 0; q < 6; q++) {
        int i = lane * 6 + q;
        if (i < NBLK) hist_g[b * NBLK + i] = run;
        run += v[q];
    }
}

// C: scatter items into bucket-ordered packed array
__global__ __launch_bounds__(256) void bin_scatter(const int* __restrict__ ei0,
        const int* __restrict__ ei1, const int* __restrict__ ei2,
        const int* __restrict__ A1r, const int* __restrict__ A1c, const float* __restrict__ A1v,
        const int* __restrict__ A2r, const int* __restrict__ A2c, const float* __restrict__ A2v,
        const int* __restrict__ hist_g, int* __restrict__ bpacked, float* __restrict__ bval) {
    __shared__ int cur[NBUCK];
    for (int i = threadIdx.x; i < NBUCK; i += 256) cur[i] = hist_g[i * NBLK + blockIdx.x];
    __syncthreads();
    int base = blockIdx.x * 4096;
#pragma unroll
    for (int q = 0; q < 16; q++) {
        int t = base + q * 256 + threadIdx.x;
        if (t >= ITEM_TOT) continue;
        int seg, pay;
        float val = 0.f;
        bool isv = false;
        if (t < NE0) { seg = ei0[NE0 + t]; pay = ei0[t]; }
        else if (t < NE0 + NE1) { int e = t - NE0; seg = 50000 + ei1[NE1 + e]; pay = ei1[e]; }
        else if (t < EDGE_TOT) { int e = t - (NE0 + NE1); seg = 62500 + ei2[NE2 + e]; pay = ei2[e]; }
        else if (t < EDGE_TOT + NNZ) { int k = t - EDGE_TOT; seg = NT + A1r[k]; pay = A1c[k]; val = A1v[k]; isv = true; }
        else { int k = t - (EDGE_TOT + NNZ); seg = NT + N0 + A2r[k]; pay = A2c[k]; val = A2v[k]; isv = true; }
        int bk = seg >> 9;
        int p = atomicAdd(&cur[bk], 1);
        bpacked[p] = ((seg - (bk << 9)) << 16) | pay;  // seg_local<512, pay<65536
        if (isv) bval[p] = val;
    }
}

// E: per-bucket count + scan + fill; writes offs[seg]=start directly.
__global__ __launch_bounds__(256) void bucket_fill(const int* __restrict__ bpacked,
        const float* __restrict__ bval, const int* __restrict__ bbase,
        int* __restrict__ offs, int* __restrict__ csrc, float* __restrict__ cval) {
    __shared__ int cnt[SPB];
    __shared__ int wsum2[4];
    int b = blockIdx.x, tid = threadIdx.x;
    int segbase = b * SPB;
    int seglim = SEG_TOT - segbase;
    if (seglim > SPB) seglim = SPB;
    int ibeg = bbase[b], iend = bbase[b + 1];
    for (int i = tid; i < SPB; i += 256) cnt[i] = 0;
    __syncthreads();
    for (int i = ibeg + tid; i < iend; i += 256)
        atomicAdd(&cnt[bpacked[i] >> 16], 1);
    __syncthreads();
    int lane = tid & 63, wid = tid >> 6;
    int v0 = cnt[tid * 2], v1 = cnt[tid * 2 + 1];
    int ts = v0 + v1, sc = ts;
#pragma unroll
    for (int o = 1; o < 64; o <<= 1) {
        int t2 = __shfl_up(sc, o, 64);
        if (lane >= o) sc += t2;
    }
    if (lane == 63) wsum2[wid] = sc;
    __syncthreads();
    int woff = 0;
    for (int w = 0; w < wid; w++) woff += wsum2[w];
    int ex = ibeg + woff + sc - ts;  // start position of seg tid*2
    __syncthreads();
    cnt[tid * 2] = ex;
    cnt[tid * 2 + 1] = ex + v0;
    if (tid * 2 < seglim) offs[segbase + tid * 2] = ex;
    if (tid * 2 + 1 < seglim) offs[segbase + tid * 2 + 1] = ex + v0;
    if (b == NBUCK - 1 && tid == 0) offs[SEG_TOT] = ITEM_TOT;
    __syncthreads();
    for (int i = ibeg + tid; i < iend; i += 256) {
        int w2 = bpacked[i];
        int sl = w2 >> 16, pay = w2 & 0xffff;
        int p = atomicAdd(&cnt[sl], 1);
        csrc[p] = pay;
        if (segbase + sl >= NT) cval[p - EDGE_TOT] = bval[i];
    }
}

// ================= batched gathers =================
// segment n spans [offs[n], offs[n+1])

__global__ void gather6_b(const float* __restrict__ x0, const float* __restrict__ x1,
                          const float* __restrict__ x2, const int* __restrict__ offs,
                          const int* __restrict__ csrc, float* __restrict__ agg6) {
    int n = blockIdx.x * blockDim.x + threadIdx.x;
    if (n >= NT) return;
    const float* x = (n < 50000) ? x0 : (n < 62500 ? x1 : x2);
    float a0 = 0, a1 = 0, a2 = 0, a3 = 0, a4 = 0, a5 = 0;
    int b = offs[n], e = offs[n + 1];
    for (int j = b; j < e; j++) {
        const float* p = x + (size_t)csrc[j] * 6;
        a0 += p[0]; a1 += p[1]; a2 += p[2]; a3 += p[3]; a4 += p[4]; a5 += p[5];
    }
    float* o = agg6 + (size_t)n * 6;
    o[0] = a0; o[1] = a1; o[2] = a2; o[3] = a3; o[4] = a4; o[5] = a5;
}

__device__ inline void acc_u4(uint4 u, float* a) {
    a[0] += __uint_as_float(u.x << 16);
    a[1] += __uint_as_float(u.x & 0xffff0000u);
    a[2] += __uint_as_float(u.y << 16);
    a[3] += __uint_as_float(u.y & 0xffff0000u);
    a[4] += __uint_as_float(u.z << 16);
    a[5] += __uint_as_float(u.z & 0xffff0000u);
    a[6] += __uint_as_float(u.w << 16);
    a[7] += __uint_as_float(u.w & 0xffff0000u);
}

// node-major bf16 hi plane; 16 lanes/node x uint4 (8 feats), edge loop unrolled x2
__global__ __launch_bounds__(256) void gatherH_b(const unsigned short* __restrict__ h1hi,
                                                 const int* __restrict__ offs,
                                                 const int* __restrict__ csrc,
                                                 float* __restrict__ agg) {
    int t = blockIdx.x * blockDim.x + threadIdx.x;
    int n = t >> 4, g = t & 15;
    if (n >= NT) return;
    int nb = (n < 50000) ? 0 : (n < 62500 ? 50000 : 62500);
    float a[8] = {};
    int b = offs[n], e = offs[n + 1];
    int j = b;
    for (; j + 1 < e; j += 2) {
        int s0 = csrc[j], s1 = csrc[j + 1];
        uint4 u0 = *(const uint4*)(h1hi + (size_t)(nb + s0) * 128 + g * 8);
        uint4 u1 = *(const uint4*)(h1hi + (size_t)(nb + s1) * 128 + g * 8);
        acc_u4(u0, a);
        acc_u4(u1, a);
    }
    if (j < e) {
        uint4 u0 = *(const uint4*)(h1hi + (size_t)(nb + csrc[j]) * 128 + g * 8);
        acc_u4(u0, a);
    }
    float* o = agg + (size_t)n * 128 + g * 8;
    *(float4*)o = (float4){a[0], a[1], a[2], a[3]};
    *(float4*)(o + 4) = (float4){a[4], a[5], a[6], a[7]};
}

// interp: 24 threads/node, edge loop unrolled x2 for MLP
__global__ __launch_bounds__(256) void interp_b(const float* __restrict__ ecat,
                                                const int* __restrict__ offs,
                                                const int* __restrict__ csrc,
                                                const float* __restrict__ cval,
                                                float* __restrict__ i1, float* __restrict__ i2) {
    int t = blockIdx.x * blockDim.x + threadIdx.x;
    int ng = t / 24, g = t % 24;
    if (ng >= 2 * N0) return;
    int a = (ng >= N0) ? 1 : 0;
    int nl = ng - a * N0;
    const float* e = ecat + (size_t)(a ? 62500 : 50000) * 96;
    float* ob = a ? i2 : i1;
    int seg = NT + ng;
    float4 s = {0.f, 0.f, 0.f, 0.f};
    int b = offs[seg], en = offs[seg + 1];
    int j = b;
    for (; j + 1 < en; j += 2) {
        int c0 = csrc[j], c1 = csrc[j + 1];
        float v0 = cval[j - EDGE_TOT], v1 = cval[j + 1 - EDGE_TOT];
        float4 w0 = ((const float4*)(e + (size_t)c0 * 96))[g];
        float4 w1 = ((const float4*)(e + (size_t)c1 * 96))[g];
        s.x += v0 * w0.x + v1 * w1.x;
        s.y += v0 * w0.y + v1 * w1.y;
        s.z += v0 * w0.z + v1 * w1.z;
        s.w += v0 * w0.w + v1 * w1.w;
    }
    if (j < en) {
        int c0 = csrc[j];
        float v0 = cval[j - EDGE_TOT];
        float4 w0 = ((const float4*)(e + (size_t)c0 * 96))[g];
        s.x += v0 * w0.x; s.y += v0 * w0.y; s.z += v0 * w0.z; s.w += v0 * w0.w;
    }
    ((float4*)(ob + (size_t)nl * 96))[g] = s;
}

// ================= weight preconvert =================
__global__ void conv_weights(const float* __restrict__ c2Wrel, const float* __restrict__ c2Wroot,
                             const float* __restrict__ linW, const float* __restrict__ dW0,
                             unsigned short* __restrict__ c2hi, unsigned short* __restrict__ c2lo,
                             unsigned short* __restrict__ lhi, unsigned short* __restrict__ llo,
                             float* __restrict__ decWt) {
    int t = blockIdx.x * blockDim.x + threadIdx.x;
    if (t < 98304) {
        int i = t / 32768, r = t % 32768;
        int n = r / 256, k = r % 256;
        float w = (k < 128) ? c2Wrel[i * 16384 + k * 128 + n]
                            : c2Wroot[i * 16384 + (k - 128) * 128 + n];
        unsigned short hi, lo;
        split_bf16(w, hi, lo);
        c2hi[t] = hi; c2lo[t] = lo;
    } else if (t < 135168) {
        int u = t - 98304;
        int i = u / 12288, r = u % 12288;
        int n = r / 128, k = r % 128;
        unsigned short hi, lo;
        split_bf16(linW[i * 12288 + k * 96 + n], hi, lo);
        lhi[u] = hi; llo[u] = lo;
    } else if (t < 153600) {
        int u = t - 135168;
        int chn = u / 6144, r = u % 6144;
        int col = r / 96, k = r % 96;
        decWt[u] = dW0[chn * 6144 + k * 64 + col];
    }
}

// ================= conv1 (fp32, K=12) -> writes h1 as node-major bf16 planes
__global__ __launch_bounds__(256) void conv1_b(
        const float* __restrict__ agg6, const float* __restrict__ x0,
        const float* __restrict__ x1, const float* __restrict__ x2,
        const float* __restrict__ Wrel, const float* __restrict__ Wroot,
        const float* __restrict__ brel,
        unsigned short* __restrict__ h1hi, unsigned short* __restrict__ h1lo) {
    __shared__ float As[16][65];
    __shared__ float Ws[16][64];
    int bx = blockIdx.x;
    int l, lbk;
    if (bx < 782) { l = 0; lbk = bx; }
    else if (bx < 978) { l = 1; lbk = bx - 782; }
    else { l = 2; lbk = bx - 978; }
    int nb = (l == 0) ? 0 : (l == 1 ? 50000 : 62500);
    int M = (l == 0) ? N0 : (l == 1 ? N1 : N2);
    const float* xl = (l == 0) ? x0 : (l == 1 ? x1 : x2);
    const float* A1 = agg6 + (size_t)nb * 6;
    const float* W1 = Wrel + l * 768;
    const float* W2 = Wroot + l * 768;
    const float* bias = brel + l * 128;
    int m0 = lbk * 64, n0 = blockIdx.y * 64;
    int tid = threadIdx.x;
    int tm = tid >> 4, tn = tid & 15;
    float acc[4][4] = {};
#pragma unroll
    for (int q = 0; q < 4; q++) {
        int idx = tid + q * 256;
        int row = idx >> 4, kk = idx & 15;
        int m = m0 + row;
        float v = 0.f;
        if (m < M && kk < 12)
            v = (kk < 6) ? A1[(size_t)m * 6 + kk] : xl[(size_t)m * 6 + kk - 6];
        As[kk][row] = v;
    }
#pragma unroll
    for (int q = 0; q < 4; q++) {
        int idx = tid + q * 256;
        int kk = idx >> 6, nn2 = idx & 63;
        float v = 0.f;
        if (kk < 12)
            v = (kk < 6) ? W1[kk * 128 + n0 + nn2] : W2[(kk - 6) * 128 + n0 + nn2];
        Ws[kk][nn2] = v;
    }
    __syncthreads();
#pragma unroll
    for (int k = 0; k < 12; k++) {
        float av[4], wv[4];
#pragma unroll
        for (int i = 0; i < 4; i++) av[i] = As[k][tm * 4 + i];
#pragma unroll
        for (int j = 0; j < 4; j++) wv[j] = Ws[k][tn * 4 + j];
#pragma unroll
        for (int i = 0; i < 4; i++)
#pragma unroll
            for (int j = 0; j < 4; j++) acc[i][j] += av[i] * wv[j];
    }
#pragma unroll
    for (int i = 0; i < 4; i++) {
        int m = m0 + tm * 4 + i;
        if (m >= M) continue;
        unsigned short hs[4], ls[4];
#pragma unroll
        for (int j = 0; j < 4; j++) {
            float v = fmaxf(acc[i][j] + bias[n0 + tn * 4 + j], 0.f);
            split_bf16(v, hs[j], ls[j]);
        }
        uint2 ph = {(unsigned)hs[0] | ((unsigned)hs[1] << 16),
                    (unsigned)hs[2] | ((unsigned)hs[3] << 16)};
        uint2 pl = {(unsigned)ls[0] | ((unsigned)ls[1] << 16),
                    (unsigned)ls[2] | ((unsigned)ls[3] << 16)};
        size_t off = (size_t)(nb + m) * 128 + n0 + tn * 4;
        *(uint2*)(h1hi + off) = ph;
        *(uint2*)(h1lo + off) = pl;
    }
}

// ================= fused conv2+lin (split-bf16 MFMA) =================
// A-tile: kt<128 -> fp32 agg (runtime split); kt>=128 -> pre-split h1 planes.
__global__ __launch_bounds__(256) void conv2lin(
        const float* __restrict__ agg,
        const unsigned short* __restrict__ h1hi, const unsigned short* __restrict__ h1lo,
        const unsigned short* __restrict__ c2hi, const unsigned short* __restrict__ c2lo,
        const float* __restrict__ c2b,
        const unsigned short* __restrict__ lnhi, const unsigned short* __restrict__ lnlo,
        const float* __restrict__ lnb, float* __restrict__ ecat) {
    __shared__ unsigned short smem[25088];  // 50.2 KB union
    unsigned short* Ah = smem;              // 64*40
    unsigned short* Al = smem + 2560;
    unsigned short* Bh = smem + 5120;       // 128*40
    unsigned short* Bl = smem + 10240;
    unsigned short* Hh = smem;              // 64*136 (phase 2)
    unsigned short* Hl = smem + 8704;
    unsigned short* B2h = smem + 17408;     // 96*40
    unsigned short* B2l = smem + 21248;
    const int LDA = 40;

    int bx = blockIdx.x;
    int l, lbk;
    if (bx < 782) { l = 0; lbk = bx; }
    else if (bx < 978) { l = 1; lbk = bx - 782; }
    else { l = 2; lbk = bx - 978; }
    int nb = (l == 0) ? 0 : (l == 1 ? 50000 : 62500);
    int M = (l == 0) ? N0 : (l == 1 ? N1 : N2);
    const float* A1 = agg + (size_t)nb * 128;
    const unsigned short* A2h = h1hi + (size_t)nb * 128;
    const unsigned short* A2l = h1lo + (size_t)nb * 128;
    const unsigned short* W1h = c2hi + l * 32768;
    const unsigned short* W1l = c2lo + l * 32768;
    const float* b1 = c2b + l * 128;
    const unsigned short* W2h = lnhi + l * 12288;
    const unsigned short* W2l = lnlo + l * 12288;
    const float* b2 = lnb + l * 96;
    float* C = ecat + (size_t)nb * 96;
    int m0 = lbk * 64;

    int tid = threadIdx.x;
    int lane = tid & 63, wid = tid >> 6;
    int waveM = wid & 1, waveN = wid >> 1;
    int l15 = lane & 15, quad = lane >> 4;
    int arow = tid >> 2, acol = (tid & 3) * 8;
    int brow = tid >> 1, bcol = (tid & 1) * 16;

    floatx4 acc[2][4];
#pragma unroll
    for (int i = 0; i < 2; i++)
#pragma unroll
        for (int j = 0; j < 4; j++) acc[i][j] = (floatx4){0.f, 0.f, 0.f, 0.f};

    // ---- phase 1: K=256 ----
    for (int kt = 0; kt < 256; kt += 32) {
        __syncthreads();
        {
            int m = m0 + arow;
            ushort8 hv, lv;
            if (m < M) {
                int kg = kt + acol;
                if (kg < 128) {  // uniform per kt
                    const float* src = A1 + (size_t)m * 128 + kg;
                    float4 u0 = *(const float4*)src;
                    float4 u1 = *(const float4*)(src + 4);
                    float xv[8] = {u0.x, u0.y, u0.z, u0.w, u1.x, u1.y, u1.z, u1.w};
#pragma unroll
                    for (int q = 0; q < 8; q++) {
                        unsigned short h, lo2;
                        split_bf16(xv[q], h, lo2);
                        hv[q] = h; lv[q] = lo2;
                    }
                } else {
                    size_t off = (size_t)m * 128 + (kg - 128);
                    hv = *(const ushort8*)(A2h + off);
                    lv = *(const ushort8*)(A2l + off);
                }
            } else {
                hv = (ushort8)0; lv = (ushort8)0;
            }
            *(ushort8*)(&Ah[arow * LDA + acol]) = hv;
            *(ushort8*)(&Al[arow * LDA + acol]) = lv;
        }
        {
            const unsigned short* ph = W1h + (size_t)brow * 256 + kt + bcol;
            const unsigned short* pl = W1l + (size_t)brow * 256 + kt + bcol;
            *(ushort8*)(&Bh[brow * LDA + bcol]) = *(const ushort8*)ph;
            *(ushort8*)(&Bh[brow * LDA + bcol + 8]) = *(const ushort8*)(ph + 8);
            *(ushort8*)(&Bl[brow * LDA + bcol]) = *(const ushort8*)pl;
            *(ushort8*)(&Bl[brow * LDA + bcol + 8]) = *(const ushort8*)(pl + 8);
        }
        __syncthreads();
        short8 af[2][2];
#pragma unroll
        for (int mt = 0; mt < 2; mt++) {
            int r = waveM * 32 + mt * 16 + l15;
            af[mt][0] = *(const short8*)(&Ah[r * LDA + quad * 8]);
            af[mt][1] = *(const short8*)(&Al[r * LDA + quad * 8]);
        }
#pragma unroll
        for (int nt = 0; nt < 4; nt++) {
            int c = waveN * 64 + nt * 16 + l15;
            short8 bh = *(const short8*)(&Bh[c * LDA + quad * 8]);
            short8 bl = *(const short8*)(&Bl[c * LDA + quad * 8]);
#pragma unroll
            for (int mt = 0; mt < 2; mt++) {
                acc[mt][nt] = __builtin_amdgcn_mfma_f32_16x16x32_bf16(af[mt][0], bh, acc[mt][nt], 0, 0, 0);
                acc[mt][nt] = __builtin_amdgcn_mfma_f32_16x16x32_bf16(af[mt][0], bl, acc[mt][nt], 0, 0, 0);
                acc[mt][nt] = __builtin_amdgcn_mfma_f32_16x16x32_bf16(af[mt][1], bh, acc[mt][nt], 0, 0, 0);
            }
        }
    }

    // ---- transition: h2 tile -> LDS hi/lo ----
    __syncthreads();
    {
        float bs1[4];
#pragma unroll
        for (int nt = 0; nt < 4; nt++) bs1[nt] = b1[waveN * 64 + nt * 16 + l15];
#pragma unroll
        for (int mt = 0; mt < 2; mt++)
#pragma unroll
            for (int nt = 0; nt < 4; nt++)
#pragma unroll
                for (int r = 0; r < 4; r++) {
                    int row = waveM * 32 + mt * 16 + quad * 4 + r;
                    int col = waveN * 64 + nt * 16 + l15;
                    float v = fmaxf(acc[mt][nt][r] + bs1[nt], 0.f);
                    unsigned short h, lo2;
                    split_bf16(v, h, lo2);
                    Hh[row * 136 + col] = h;
                    Hl[row * 136 + col] = lo2;
                }
    }

    // ---- phase 2: K=128, J=96 ----
    floatx4 acc2[2][3];
#pragma unroll
    for (int i = 0; i < 2; i++)
#pragma unroll
        for (int j = 0; j < 3; j++) acc2[i][j] = (floatx4){0.f, 0.f, 0.f, 0.f};

    for (int kt = 0; kt < 128; kt += 32) {
        __syncthreads();
        if (brow < 96) {
            const unsigned short* ph = W2h + (size_t)brow * 128 + kt + bcol;
            const unsigned short* pl = W2l + (size_t)brow * 128 + kt + bcol;
            *(ushort8*)(&B2h[brow * LDA + bcol]) = *(const ushort8*)ph;
            *(ushort8*)(&B2h[brow * LDA + bcol + 8]) = *(const ushort8*)(ph + 8);
            *(ushort8*)(&B2l[brow * LDA + bcol]) = *(const ushort8*)pl;
            *(ushort8*)(&B2l[brow * LDA + bcol + 8]) = *(const ushort8*)(pl + 8);
        }
        __syncthreads();
        short8 af2[2][2];
#pragma unroll
        for (int mt = 0; mt < 2; mt++) {
            int r = waveM * 32 + mt * 16 + l15;
            af2[mt][0] = *(const short8*)(&Hh[r * 136 + kt + quad * 8]);
            af2[mt][1] = *(const short8*)(&Hl[r * 136 + kt + quad * 8]);
        }
#pragma unroll
        for (int nt = 0; nt < 3; nt++) {
            int c = waveN * 48 + nt * 16 + l15;
            short8 bh = *(const short8*)(&B2h[c * LDA + quad * 8]);
            short8 bl = *(const short8*)(&B2l[c * LDA + quad * 8]);
#pragma unroll
            for (int mt = 0; mt < 2; mt++) {
                acc2[mt][nt] = __builtin_amdgcn_mfma_f32_16x16x32_bf16(af2[mt][0], bh, acc2[mt][nt], 0, 0, 0);
                acc2[mt][nt] = __builtin_amdgcn_mfma_f32_16x16x32_bf16(af2[mt][0], bl, acc2[mt][nt], 0, 0, 0);
                acc2[mt][nt] = __builtin_amdgcn_mfma_f32_16x16x32_bf16(af2[mt][1], bh, acc2[mt][nt], 0, 0, 0);
            }
        }
    }

    // ---- epilogue ----
    float bs2[3];
#pragma unroll
    for (int nt = 0; nt < 3; nt++) bs2[nt] = b2[waveN * 48 + nt * 16 + l15];
#pragma unroll
    for (int mt = 0; mt < 2; mt++)
#pragma unroll
        for (int r = 0; r < 4; r++) {
            int grow = m0 + waveM * 32 + mt * 16 + quad * 4 + r;
            if (grow >= M) continue;
#pragma unroll
            for (int nt = 0; nt < 3; nt++) {
                int col = waveN * 48 + nt * 16 + l15;
                C[(size_t)grow * 96 + col] = acc2[mt][nt][r] + bs2[nt];
            }
        }
}

// ================= MFMA decoder =================
__global__ __launch_bounds__(256) void decoder_mfma(
        const float* __restrict__ e0, const float* __restrict__ i1,
        const float* __restrict__ i2, const float* __restrict__ decWt,
        const float* __restrict__ b0, const float* __restrict__ Wout,
        const float* __restrict__ bout, float* __restrict__ out, int N) {
    __shared__ float As[6400];   // [row][k], pitch 100
    __shared__ float Bs[6400];   // [col][k], pitch 100
    __shared__ float red[64][2];
    __shared__ float sb0[64], sWo[64];
    int ch = blockIdx.y;
    int tid = threadIdx.x;
    int m0 = blockIdx.x * 64;

    for (int idx = tid; idx < 1536; idx += 256) {
        int col = idx / 24, k0 = (idx % 24) * 4;
        *(float4*)(&Bs[col * 100 + k0]) = *(const float4*)(decWt + ch * 6144 + col * 96 + k0);
    }
    if (tid < 64) { sb0[tid] = b0[ch * 64 + tid]; sWo[tid] = Wout[ch * 64 + tid]; }
    for (int idx = tid; idx < 1536; idx += 256) {
        int row = idx / 24, k0 = (idx % 24) * 4;
        int m = m0 + row;
        float4 v = {0.f, 0.f, 0.f, 0.f};
        if (m < N) {
            const float* base = (k0 < 32) ? e0 : (k0 < 64 ? i1 : i2);
            v = *(const float4*)(base + (size_t)m * 96 + ch * 32 + (k0 & 31));
        }
        *(float4*)(&As[row * 100 + k0]) = v;
    }
    __syncthreads();

    int lane = tid & 63, wid = tid >> 6;
    int waveM = wid & 1, waveN = wid >> 1;
    int l15 = lane & 15, quad = lane >> 4;
    floatx4 acc[2][2];
#pragma unroll
    for (int i = 0; i < 2; i++)
#pragma unroll
        for (int j = 0; j < 2; j++) acc[i][j] = (floatx4){0.f, 0.f, 0.f, 0.f};

#pragma unroll
    for (int kt = 0; kt < 96; kt += 32) {
        short8 ah[2], al[2];
#pragma unroll
        for (int mt = 0; mt < 2; mt++) {
            int r = waveM * 32 + mt * 16 + l15;
            split8(&As[r * 100 + kt + quad * 8], ah[mt], al[mt]);
        }
#pragma unroll
        for (int nt = 0; nt < 2; nt++) {
            int c = waveN * 32 + nt * 16 + l15;
            short8 bh, bl;
            split8(&Bs[c * 100 + kt + quad * 8], bh, bl);
#pragma unroll
            for (int mt = 0; mt < 2; mt++) {
                acc[mt][nt] = __builtin_amdgcn_mfma_f32_16x16x32_bf16(ah[mt], bh, acc[mt][nt], 0, 0, 0);
                acc[mt][nt] = __builtin_amdgcn_mfma_f32_16x16x32_bf16(ah[mt], bl, acc[mt][nt], 0, 0, 0);
                acc[mt][nt] = __builtin_amdgcn_mfma_f32_16x16x32_bf16(al[mt], bh, acc[mt][nt], 0, 0, 0);
            }
        }
    }

    float cb0[2], cwo[2];
#pragma unroll
    for (int nt = 0; nt < 2; nt++) {
        int col = waveN * 32 + nt * 16 + l15;
        cb0[nt] = sb0[col]; cwo[nt] = sWo[col];
    }
    float p[2][4];
#pragma unroll
    for (int mt = 0; mt < 2; mt++)
#pragma unroll
        for (int r = 0; r < 4; r++) {
            float s = 0.f;
#pragma unroll
            for (int nt = 0; nt < 2; nt++) {
                float h = acc[mt][nt][r] + cb0[nt];
                h = h > 0.f ? h : (expf(h) - 1.0f);
                s += h * cwo[nt];
            }
            p[mt][r] = s;
        }
#pragma unroll
    for (int mt = 0; mt < 2; mt++)
#pragma unroll
        for (int r = 0; r < 4; r++) {
#pragma unroll
            for (int msk = 1; msk < 16; msk <<= 1)
                p[mt][r] += __shfl_xor(p[mt][r], msk, 64);
        }
    if (l15 == 0) {
#pragma unroll
        for (int mt = 0; mt < 2; mt++)
#pragma unroll
            for (int r = 0; r < 4; r++) {
                int row = waveM * 32 + mt * 16 + quad * 4 + r;
                red[row][waveN] = p[mt][r];
            }
    }
    __syncthreads();
    if (tid < 64) {
        int m = m0 + tid;
        if (m < N) out[(size_t)m * 3 + ch] = red[tid][0] + red[tid][1] + bout[ch];
    }
}

// ================= host launch =================

extern "C" void kernel_launch(void* const* d_in, const int* in_sizes, int n_in,
                              void* d_out, int out_size, void* d_ws, size_t ws_size,
                              hipStream_t stream) {
    const float* x0 = (const float*)d_in[0];
    const float* x1 = (const float*)d_in[1];
    const float* x2 = (const float*)d_in[2];
    const int* ei0 = (const int*)d_in[3];
    const int* ei1 = (const int*)d_in[4];
    const int* ei2 = (const int*)d_in[5];
    const int* A1r = (const int*)d_in[6];
    const int* A1c = (const int*)d_in[7];
    const float* A1v = (const float*)d_in[8];
    const int* A2r = (const int*)d_in[9];
    const int* A2c = (const int*)d_in[10];
    const float* A2v = (const float*)d_in[11];
    const float* c1Wrel = (const float*)d_in[12];
    const float* c1brel = (const float*)d_in[13];
    const float* c1Wroot = (const float*)d_in[14];
    const float* c2Wrel = (const float*)d_in[15];
    const float* c2brel = (const float*)d_in[16];
    const float* c2Wroot = (const float*)d_in[17];
    const float* linW = (const float*)d_in[18];
    const float* linb = (const float*)d_in[19];
    const float* dW0 = (const float*)d_in[20];
    const float* db0 = (const float*)d_in[21];
    const float* dWout = (const float*)d_in[22];
    const float* dbout = (const float*)d_in[23];
    float* out = (float*)d_out;

    // ---- workspace (float words) ----
    float* ws = (float*)d_ws;
    float* agg6 = ws;                            // [0, 400,000)
    unsigned short* h1hi = (unsigned short*)(ws + 400000);   // node-major, 8.4M ushorts
    unsigned short* h1lo = (unsigned short*)(ws + 4600000);  // node-major, 8.4M ushorts
    float* aggH = ws + 8800000;                  // 8.4M words [8.8M, 17.2M)
    float* ecat = ws + 17200000;                 // 6.3M words
    // binned intermediates overlay aggH (dead before gatherH writes aggH)
    int* bpacked = (int*)(ws + 8800000);         // 1,450,000
    float* bval = ws + 8800000 + 1450000;        // 1,450,000 (ends 11.7M < 17.2M)
    float* i1 = aggH;                            // overlay (dead after conv2lin)
    float* i2 = ws + 400000;                     // overlays h1 planes (dead after conv2lin)
    int* hist_g = (int*)(ws + 23500000);         // NBUCK*NBLK = 115,020
    int* btot = (int*)(ws + 23615020);           // 324
    int* bbase = (int*)(ws + 23615344);          // 325
    int* offs = (int*)(ws + 23665632);           // 165,626
    int* csrc = (int*)(ws + 23831264);           // 1,450,000
    float* cval = ws + 25281392;                 // 400,000
    unsigned short* c2hi = (unsigned short*)(ws + 25681392); // 98,304 ushort
    unsigned short* c2lo = c2hi + 98304;
    unsigned short* lnhi = c2lo + 98304;                     // 36,864 ushort
    unsigned short* lnlo = lnhi + 36864;
    float* decWt = ws + 25681392 + 135168;       // 18,432 floats; ends ~25,834,992 (~103.3 MB)

    conv_weights<<<(153600 + 255) / 256, 256, 0, stream>>>(
        c2Wrel, c2Wroot, linW, dW0, c2hi, c2lo, lnhi, lnlo, decWt);

    // ---- binned CSR build ----
    bin_hist<<<NBLK, 256, 0, stream>>>(ei0, ei1, ei2, A1r, A2r, hist_g);
    bucket_tot_k<<<NBUCK, 64, 0, stream>>>(hist_g, btot);
    hist_scan<<<NBUCK, 64, 0, stream>>>(hist_g, btot, bbase);
    bin_scatter<<<NBLK, 256, 0, stream>>>(ei0, ei1, ei2, A1r, A1c, A1v,
                                          A2r, A2c, A2v, hist_g, bpacked, bval);
    bucket_fill<<<NBUCK, 256, 0, stream>>>(bpacked, bval, bbase, offs, csrc, cval);

    // ---- encoder ----
    gather6_b<<<(NT + 255) / 256, 256, 0, stream>>>(x0, x1, x2, offs, csrc, agg6);
    dim3 g1(1027, 2);
    conv1_b<<<g1, 256, 0, stream>>>(agg6, x0, x1, x2, c1Wrel, c1Wroot, c1brel, h1hi, h1lo);
    gatherH_b<<<((size_t)NT * 16 + 255) / 256, 256, 0, stream>>>(h1hi, offs, csrc, aggH);
    conv2lin<<<1027, 256, 0, stream>>>(aggH, h1hi, h1lo, c2hi, c2lo, c2brel,
                                       lnhi, lnlo, linb, ecat);

    // ---- interpolation (i1 over aggH, i2 over h1 planes — both dead now) ----
    interp_b<<<((size_t)2 * N0 * 24 + 255) / 256, 256, 0, stream>>>(
        ecat, offs, csrc, cval, i1, i2);

    // ---- decoder ----
    dim3 gd(782, 3);
    decoder_mfma<<<gd, 256, 0, stream>>>(ecat, i1, i2, decWt, db0, dWout, dbout, out, N0);
}

// Round 13
// 306.473 us; speedup vs baseline: 1.1926x; 1.0097x over previous
//
#include <hip/hip_runtime.h>
#include <math.h>

#define N0 50000
#define N1 12500
#define N2 3125
#define NNZ 200000
#define NE0 800000
#define NE1 200000
#define NE2 50000
#define NT 65625           // N0+N1+N2
#define SEG_TOT 165625     // NT + 2*N0
#define EDGE_TOT 1050000   // NE0+NE1+NE2
#define ITEM_TOT 1450000   // EDGE_TOT + 2*NNZ
#define NBUCK 324          // ceil(SEG_TOT/512)
#define SPB 512            // segs per bucket
#define NBLK 355           // ceil(ITEM_TOT/4096)

typedef __attribute__((ext_vector_type(8))) short short8;
typedef __attribute__((ext_vector_type(8))) unsigned short ushort8;
typedef __attribute__((ext_vector_type(4))) float floatx4;

__device__ inline void split_bf16(float x, unsigned short& hi, unsigned short& lo) {
    unsigned xb = __float_as_uint(x);
    hi = (unsigned short)(xb >> 16);
    float hf = __uint_as_float((unsigned)hi << 16);
    lo = (unsigned short)(__float_as_uint(x - hf) >> 16);
}

// split 8 contiguous fp32 (LDS) into hi/lo bf16 frags
__device__ inline void split8(const float* p, short8& hi, short8& lo) {
    float4 u0 = *(const float4*)p;
    float4 u1 = *(const float4*)(p + 4);
    float f[8] = {u0.x, u0.y, u0.z, u0.w, u1.x, u1.y, u1.z, u1.w};
#pragma unroll
    for (int j = 0; j < 8; j++) {
        unsigned short h, l;
        split_bf16(f[j], h, l);
        hi[j] = (short)h; lo[j] = (short)l;
    }
}

// ================= binned CSR build =================
// seg space: [0,50000) L0 nodes, [50000,62500) L1, [62500,65625) L2,
// [65625,115625) interp1 rows, [115625,165625) interp2 rows.

__device__ inline int item_seg(int t, const int* __restrict__ ei0,
                               const int* __restrict__ ei1, const int* __restrict__ ei2,
                               const int* __restrict__ A1r, const int* __restrict__ A2r) {
    if (t < NE0) return ei0[NE0 + t];
    if (t < NE0 + NE1) return 50000 + ei1[NE1 + (t - NE0)];
    if (t < EDGE_TOT) return 62500 + ei2[NE2 + (t - (NE0 + NE1))];
    if (t < EDGE_TOT + NNZ) return NT + A1r[t - EDGE_TOT];
    return NT + N0 + A2r[t - (EDGE_TOT + NNZ)];
}

// A: per-block bucket histogram -> hist_g[bucket*NBLK + blk]; also bucket totals
__global__ __launch_bounds__(256) void bin_hist(const int* __restrict__ ei0,
        const int* __restrict__ ei1, const int* __restrict__ ei2,
        const int* __restrict__ A1r, const int* __restrict__ A2r,
        int* __restrict__ hist_g, int* __restrict__ btot) {
    __shared__ int h[NBUCK];
    for (int i = threadIdx.x; i < NBUCK; i += 256) h[i] = 0;
    __syncthreads();
    int base = blockIdx.x * 4096;
#pragma unroll
    for (int q = 0; q < 16; q++) {
        int t = base + q * 256 + threadIdx.x;
        if (t < ITEM_TOT) atomicAdd(&h[item_seg(t, ei0, ei1, ei2, A1r, A2r) >> 9], 1);
    }
    __syncthreads();
    for (int i = threadIdx.x; i < NBUCK; i += 256) {
        int v = h[i];
        hist_g[i * NBLK + blockIdx.x] = v;
        if (v) atomicAdd(&btot[i], v);
    }
}

// B3: per-bucket exclusive scan of hist_g row + bucket_base
__global__ void hist_scan(int* __restrict__ hist_g, const int* __restrict__ btot,
                          int* __restrict__ bbase) {
    int b = blockIdx.x, lane = threadIdx.x;
    int s = 0;
    for (int j = lane; j < b; j += 64) s += btot[j];
#pragma unroll
    for (int o = 32; o > 0; o >>= 1) s += __shfl_down(s, o, 64);
    int base = __shfl(s, 0, 64);
    if (lane == 0) {
        bbase[b] = base;
        if (b == NBUCK - 1) bbase[NBUCK] = ITEM_TOT;
    }
    int v[6], ts = 0;
#pragma unroll
    for (int q = 0; q < 6; q++) {
        int i = lane * 6 + q;
        v[q] = (i < NBLK) ? hist_g[b * NBLK + i] : 0;
        ts += v[q];
    }
    int sc = ts;
#pragma unroll
    for (int o = 1; o < 64; o <<= 1) {
        int t2 = __shfl_up(sc, o, 64);
        if (lane >= o) sc += t2;
    }
    int run = base + sc - ts;
#pragma unroll
    for (int q = 0; q < 6; q++) {
        int i = lane * 6 + q;
        if (i < NBLK) hist_g[b * NBLK + i] = run;
        run += v[q];
    }
}

// C: scatter items into bucket-ordered packed array
__global__ __launch_bounds__(256) void bin_scatter(const int* __restrict__ ei0,
        const int* __restrict__ ei1, const int* __restrict__ ei2,
        const int* __restrict__ A1r, const int* __restrict__ A1c, const float* __restrict__ A1v,
        const int* __restrict__ A2r, const int* __restrict__ A2c, const float* __restrict__ A2v,
        const int* __restrict__ hist_g, int* __restrict__ bpacked, float* __restrict__ bval) {
    __shared__ int cur[NBUCK];
    for (int i = threadIdx.x; i < NBUCK; i += 256) cur[i] = hist_g[i * NBLK + blockIdx.x];
    __syncthreads();
    int base = blockIdx.x * 4096;
#pragma unroll
    for (int q = 0; q < 16; q++) {
        int t = base + q * 256 + threadIdx.x;
        if (t >= ITEM_TOT) continue;
        int seg, pay;
        float val = 0.f;
        bool isv = false;
        if (t < NE0) { seg = ei0[NE0 + t]; pay = ei0[t]; }
        else if (t < NE0 + NE1) { int e = t - NE0; seg = 50000 + ei1[NE1 + e]; pay = ei1[e]; }
        else if (t < EDGE_TOT) { int e = t - (NE0 + NE1); seg = 62500 + ei2[NE2 + e]; pay = ei2[e]; }
        else if (t < EDGE_TOT + NNZ) { int k = t - EDGE_TOT; seg = NT + A1r[k]; pay = A1c[k]; val = A1v[k]; isv = true; }
        else { int k = t - (EDGE_TOT + NNZ); seg = NT + N0 + A2r[k]; pay = A2c[k]; val = A2v[k]; isv = true; }
        int bk = seg >> 9;
        int p = atomicAdd(&cur[bk], 1);
        bpacked[p] = ((seg - (bk << 9)) << 16) | pay;  // seg_local<512, pay<65536
        if (isv) bval[p] = val;
    }
}

// E: per-bucket count + scan + fill; writes offs[seg]=start directly.
__global__ __launch_bounds__(256) void bucket_fill(const int* __restrict__ bpacked,
        const float* __restrict__ bval, const int* __restrict__ bbase,
        int* __restrict__ offs, int* __restrict__ csrc, float* __restrict__ cval) {
    __shared__ int cnt[SPB];
    __shared__ int wsum2[4];
    int b = blockIdx.x, tid = threadIdx.x;
    int segbase = b * SPB;
    int seglim = SEG_TOT - segbase;
    if (seglim > SPB) seglim = SPB;
    int ibeg = bbase[b], iend = bbase[b + 1];
    for (int i = tid; i < SPB; i += 256) cnt[i] = 0;
    __syncthreads();
    for (int i = ibeg + tid; i < iend; i += 256)
        atomicAdd(&cnt[bpacked[i] >> 16], 1);
    __syncthreads();
    int lane = tid & 63, wid = tid >> 6;
    int v0 = cnt[tid * 2], v1 = cnt[tid * 2 + 1];
    int ts = v0 + v1, sc = ts;
#pragma unroll
    for (int o = 1; o < 64; o <<= 1) {
        int t2 = __shfl_up(sc, o, 64);
        if (lane >= o) sc += t2;
    }
    if (lane == 63) wsum2[wid] = sc;
    __syncthreads();
    int woff = 0;
    for (int w = 0; w < wid; w++) woff += wsum2[w];
    int ex = ibeg + woff + sc - ts;  // start position of seg tid*2
    __syncthreads();
    cnt[tid * 2] = ex;
    cnt[tid * 2 + 1] = ex + v0;
    if (tid * 2 < seglim) offs[segbase + tid * 2] = ex;
    if (tid * 2 + 1 < seglim) offs[segbase + tid * 2 + 1] = ex + v0;
    if (b == NBUCK - 1 && tid == 0) offs[SEG_TOT] = ITEM_TOT;
    __syncthreads();
    for (int i = ibeg + tid; i < iend; i += 256) {
        int w2 = bpacked[i];
        int sl = w2 >> 16, pay = w2 & 0xffff;
        int p = atomicAdd(&cnt[sl], 1);
        csrc[p] = pay;
        if (segbase + sl >= NT) cval[p - EDGE_TOT] = bval[i];
    }
}

// ================= batched gathers =================
// segment n spans [offs[n], offs[n+1])

__device__ inline void acc_u4(uint4 u, float* a) {
    a[0] += __uint_as_float(u.x << 16);
    a[1] += __uint_as_float(u.x & 0xffff0000u);
    a[2] += __uint_as_float(u.y << 16);
    a[3] += __uint_as_float(u.y & 0xffff0000u);
    a[4] += __uint_as_float(u.z << 16);
    a[5] += __uint_as_float(u.z & 0xffff0000u);
    a[6] += __uint_as_float(u.w << 16);
    a[7] += __uint_as_float(u.w & 0xffff0000u);
}

// node-major bf16 hi plane; 16 lanes/node x uint4 (8 feats), edge loop unrolled x4
__global__ __launch_bounds__(256) void gatherH_b(const unsigned short* __restrict__ h1hi,
                                                 const int* __restrict__ offs,
                                                 const int* __restrict__ csrc,
                                                 float* __restrict__ agg) {
    int t = blockIdx.x * blockDim.x + threadIdx.x;
    int n = t >> 4, g = t & 15;
    if (n >= NT) return;
    int nb = (n < 50000) ? 0 : (n < 62500 ? 50000 : 62500);
    float a[8] = {};
    int b = offs[n], e = offs[n + 1];
    int j = b;
    for (; j + 3 < e; j += 4) {
        int s0 = csrc[j], s1 = csrc[j + 1], s2 = csrc[j + 2], s3 = csrc[j + 3];
        uint4 u0 = *(const uint4*)(h1hi + (size_t)(nb + s0) * 128 + g * 8);
        uint4 u1 = *(const uint4*)(h1hi + (size_t)(nb + s1) * 128 + g * 8);
        uint4 u2 = *(const uint4*)(h1hi + (size_t)(nb + s2) * 128 + g * 8);
        uint4 u3 = *(const uint4*)(h1hi + (size_t)(nb + s3) * 128 + g * 8);
        acc_u4(u0, a);
        acc_u4(u1, a);
        acc_u4(u2, a);
        acc_u4(u3, a);
    }
    for (; j < e; j++) {
        uint4 u0 = *(const uint4*)(h1hi + (size_t)(nb + csrc[j]) * 128 + g * 8);
        acc_u4(u0, a);
    }
    float* o = agg + (size_t)n * 128 + g * 8;
    *(float4*)o = (float4){a[0], a[1], a[2], a[3]};
    *(float4*)(o + 4) = (float4){a[4], a[5], a[6], a[7]};
}

// interp: 24 threads/node, edge loop unrolled x2 for MLP
__global__ __launch_bounds__(256) void interp_b(const float* __restrict__ ecat,
                                                const int* __restrict__ offs,
                                                const int* __restrict__ csrc,
                                                const float* __restrict__ cval,
                                                float* __restrict__ i1, float* __restrict__ i2) {
    int t = blockIdx.x * blockDim.x + threadIdx.x;
    int ng = t / 24, g = t % 24;
    if (ng >= 2 * N0) return;
    int a = (ng >= N0) ? 1 : 0;
    int nl = ng - a * N0;
    const float* e = ecat + (size_t)(a ? 62500 : 50000) * 96;
    float* ob = a ? i2 : i1;
    int seg = NT + ng;
    float4 s = {0.f, 0.f, 0.f, 0.f};
    int b = offs[seg], en = offs[seg + 1];
    int j = b;
    for (; j + 1 < en; j += 2) {
        int c0 = csrc[j], c1 = csrc[j + 1];
        float v0 = cval[j - EDGE_TOT], v1 = cval[j + 1 - EDGE_TOT];
        float4 w0 = ((const float4*)(e + (size_t)c0 * 96))[g];
        float4 w1 = ((const float4*)(e + (size_t)c1 * 96))[g];
        s.x += v0 * w0.x + v1 * w1.x;
        s.y += v0 * w0.y + v1 * w1.y;
        s.z += v0 * w0.z + v1 * w1.z;
        s.w += v0 * w0.w + v1 * w1.w;
    }
    if (j < en) {
        int c0 = csrc[j];
        float v0 = cval[j - EDGE_TOT];
        float4 w0 = ((const float4*)(e + (size_t)c0 * 96))[g];
        s.x += v0 * w0.x; s.y += v0 * w0.y; s.z += v0 * w0.z; s.w += v0 * w0.w;
    }
    ((float4*)(ob + (size_t)nl * 96))[g] = s;
}

// ================= weight preconvert (also zeroes btot) =================
__global__ void conv_weights(const float* __restrict__ c2Wrel, const float* __restrict__ c2Wroot,
                             const float* __restrict__ linW, const float* __restrict__ dW0,
                             unsigned short* __restrict__ c2hi, unsigned short* __restrict__ c2lo,
                             unsigned short* __restrict__ lhi, unsigned short* __restrict__ llo,
                             float* __restrict__ decWt, int* __restrict__ btot) {
    int t = blockIdx.x * blockDim.x + threadIdx.x;
    if (t <= NBUCK) btot[t] = 0;
    if (t < 98304) {
        int i = t / 32768, r = t % 32768;
        int n = r / 256, k = r % 256;
        float w = (k < 128) ? c2Wrel[i * 16384 + k * 128 + n]
                            : c2Wroot[i * 16384 + (k - 128) * 128 + n];
        unsigned short hi, lo;
        split_bf16(w, hi, lo);
        c2hi[t] = hi; c2lo[t] = lo;
    } else if (t < 135168) {
        int u = t - 98304;
        int i = u / 12288, r = u % 12288;
        int n = r / 128, k = r % 128;
        unsigned short hi, lo;
        split_bf16(linW[i * 12288 + k * 96 + n], hi, lo);
        lhi[u] = hi; llo[u] = lo;
    } else if (t < 153600) {
        int u = t - 135168;
        int chn = u / 6144, r = u % 6144;
        int col = r / 96, k = r % 96;
        decWt[u] = dW0[chn * 6144 + k * 64 + col];
    }
}

// ===== conv1 (fp32, K=12) with fused CSR gather -> node-major bf16 planes ====
__global__ __launch_bounds__(256) void conv1_b(
        const int* __restrict__ offs, const int* __restrict__ csrc,
        const float* __restrict__ x0, const float* __restrict__ x1,
        const float* __restrict__ x2,
        const float* __restrict__ Wrel, const float* __restrict__ Wroot,
        const float* __restrict__ brel,
        unsigned short* __restrict__ h1hi, unsigned short* __restrict__ h1lo) {
    __shared__ float As[12][65];
    __shared__ float Ws[12][64];
    int bx = blockIdx.x;
    int l, lbk;
    if (bx < 782) { l = 0; lbk = bx; }
    else if (bx < 978) { l = 1; lbk = bx - 782; }
    else { l = 2; lbk = bx - 978; }
    int nb = (l == 0) ? 0 : (l == 1 ? 50000 : 62500);
    int M = (l == 0) ? N0 : (l == 1 ? N1 : N2);
    const float* xl = (l == 0) ? x0 : (l == 1 ? x1 : x2);
    const float* W1 = Wrel + l * 768;
    const float* W2 = Wroot + l * 768;
    const float* bias = brel + l * 128;
    int m0 = lbk * 64, n0 = blockIdx.y * 64;
    int tid = threadIdx.x;

    // fused gather: 4 threads/row compute segment partials, shfl-reduce
    {
        int row = tid >> 2, sub = tid & 3;
        int m = m0 + row;
        float a6[6] = {};
        if (m < M) {
            int jb = offs[nb + m], je = offs[nb + m + 1];
            for (int j = jb + sub; j < je; j += 4) {
                const float* p = xl + (size_t)csrc[j] * 6;
                a6[0] += p[0]; a6[1] += p[1]; a6[2] += p[2];
                a6[3] += p[3]; a6[4] += p[4]; a6[5] += p[5];
            }
        }
#pragma unroll
        for (int msk = 1; msk < 4; msk <<= 1) {
#pragma unroll
            for (int q = 0; q < 6; q++) a6[q] += __shfl_xor(a6[q], msk, 64);
        }
        if (sub == 0) {
#pragma unroll
            for (int q = 0; q < 6; q++) As[q][row] = (m < M) ? a6[q] : 0.f;
        } else if (sub == 1) {
#pragma unroll
            for (int q = 0; q < 6; q++)
                As[6 + q][row] = (m < M) ? xl[(size_t)m * 6 + q] : 0.f;
        }
    }
    // W staging (12 x 64)
    for (int idx = tid; idx < 768; idx += 256) {
        int kk = idx >> 6, nn2 = idx & 63;
        Ws[kk][nn2] = (kk < 6) ? W1[kk * 128 + n0 + nn2] : W2[(kk - 6) * 128 + n0 + nn2];
    }
    __syncthreads();

    int tm = tid >> 4, tn = tid & 15;
    float acc[4][4] = {};
#pragma unroll
    for (int k = 0; k < 12; k++) {
        float av[4], wv[4];
#pragma unroll
        for (int i = 0; i < 4; i++) av[i] = As[k][tm * 4 + i];
#pragma unroll
        for (int j = 0; j < 4; j++) wv[j] = Ws[k][tn * 4 + j];
#pragma unroll
        for (int i = 0; i < 4; i++)
#pragma unroll
            for (int j = 0; j < 4; j++) acc[i][j] += av[i] * wv[j];
    }
#pragma unroll
    for (int i = 0; i < 4; i++) {
        int m = m0 + tm * 4 + i;
        if (m >= M) continue;
        unsigned short hs[4], ls[4];
#pragma unroll
        for (int j = 0; j < 4; j++) {
            float v = fmaxf(acc[i][j] + bias[n0 + tn * 4 + j], 0.f);
            split_bf16(v, hs[j], ls[j]);
        }
        uint2 ph = {(unsigned)hs[0] | ((unsigned)hs[1] << 16),
                    (unsigned)hs[2] | ((unsigned)hs[3] << 16)};
        uint2 pl = {(unsigned)ls[0] | ((unsigned)ls[1] << 16),
                    (unsigned)ls[2] | ((unsigned)ls[3] << 16)};
        size_t off = (size_t)(nb + m) * 128 + n0 + tn * 4;
        *(uint2*)(h1hi + off) = ph;
        *(uint2*)(h1lo + off) = pl;
    }
}

// ================= fused conv2+lin (split-bf16 MFMA) =================
// A-tile: kt<128 -> fp32 agg (runtime split); kt>=128 -> pre-split h1 planes.
__global__ __launch_bounds__(256) void conv2lin(
        const float* __restrict__ agg,
        const unsigned short* __restrict__ h1hi, const unsigned short* __restrict__ h1lo,
        const unsigned short* __restrict__ c2hi, const unsigned short* __restrict__ c2lo,
        const float* __restrict__ c2b,
        const unsigned short* __restrict__ lnhi, const unsigned short* __restrict__ lnlo,
        const float* __restrict__ lnb, float* __restrict__ ecat) {
    __shared__ unsigned short smem[25088];  // 50.2 KB union
    unsigned short* Ah = smem;              // 64*40
    unsigned short* Al = smem + 2560;
    unsigned short* Bh = smem + 5120;       // 128*40
    unsigned short* Bl = smem + 10240;
    unsigned short* Hh = smem;              // 64*136 (phase 2)
    unsigned short* Hl = smem + 8704;
    unsigned short* B2h = smem + 17408;     // 96*40
    unsigned short* B2l = smem + 21248;
    const int LDA = 40;

    int bx = blockIdx.x;
    int l, lbk;
    if (bx < 782) { l = 0; lbk = bx; }
    else if (bx < 978) { l = 1; lbk = bx - 782; }
    else { l = 2; lbk = bx - 978; }
    int nb = (l == 0) ? 0 : (l == 1 ? 50000 : 62500);
    int M = (l == 0) ? N0 : (l == 1 ? N1 : N2);
    const float* A1 = agg + (size_t)nb * 128;
    const unsigned short* A2h = h1hi + (size_t)nb * 128;
    const unsigned short* A2l = h1lo + (size_t)nb * 128;
    const unsigned short* W1h = c2hi + l * 32768;
    const unsigned short* W1l = c2lo + l * 32768;
    const float* b1 = c2b + l * 128;
    const unsigned short* W2h = lnhi + l * 12288;
    const unsigned short* W2l = lnlo + l * 12288;
    const float* b2 = lnb + l * 96;
    float* C = ecat + (size_t)nb * 96;
    int m0 = lbk * 64;

    int tid = threadIdx.x;
    int lane = tid & 63, wid = tid >> 6;
    int waveM = wid & 1, waveN = wid >> 1;
    int l15 = lane & 15, quad = lane >> 4;
    int arow = tid >> 2, acol = (tid & 3) * 8;
    int brow = tid >> 1, bcol = (tid & 1) * 16;

    floatx4 acc[2][4];
#pragma unroll
    for (int i = 0; i < 2; i++)
#pragma unroll
        for (int j = 0; j < 4; j++) acc[i][j] = (floatx4){0.f, 0.f, 0.f, 0.f};

    // ---- phase 1: K=256 ----
    for (int kt = 0; kt < 256; kt += 32) {
        __syncthreads();
        {
            int m = m0 + arow;
            ushort8 hv, lv;
            if (m < M) {
                int kg = kt + acol;
                if (kg < 128) {  // uniform per kt
                    const float* src = A1 + (size_t)m * 128 + kg;
                    float4 u0 = *(const float4*)src;
                    float4 u1 = *(const float4*)(src + 4);
                    float xv[8] = {u0.x, u0.y, u0.z, u0.w, u1.x, u1.y, u1.z, u1.w};
#pragma unroll
                    for (int q = 0; q < 8; q++) {
                        unsigned short h, lo2;
                        split_bf16(xv[q], h, lo2);
                        hv[q] = h; lv[q] = lo2;
                    }
                } else {
                    size_t off = (size_t)m * 128 + (kg - 128);
                    hv = *(const ushort8*)(A2h + off);
                    lv = *(const ushort8*)(A2l + off);
                }
            } else {
                hv = (ushort8)0; lv = (ushort8)0;
            }
            *(ushort8*)(&Ah[arow * LDA + acol]) = hv;
            *(ushort8*)(&Al[arow * LDA + acol]) = lv;
        }
        {
            const unsigned short* ph = W1h + (size_t)brow * 256 + kt + bcol;
            const unsigned short* pl = W1l + (size_t)brow * 256 + kt + bcol;
            *(ushort8*)(&Bh[brow * LDA + bcol]) = *(const ushort8*)ph;
            *(ushort8*)(&Bh[brow * LDA + bcol + 8]) = *(const ushort8*)(ph + 8);
            *(ushort8*)(&Bl[brow * LDA + bcol]) = *(const ushort8*)pl;
            *(ushort8*)(&Bl[brow * LDA + bcol + 8]) = *(const ushort8*)(pl + 8);
        }
        __syncthreads();
        short8 af[2][2];
#pragma unroll
        for (int mt = 0; mt < 2; mt++) {
            int r = waveM * 32 + mt * 16 + l15;
            af[mt][0] = *(const short8*)(&Ah[r * LDA + quad * 8]);
            af[mt][1] = *(const short8*)(&Al[r * LDA + quad * 8]);
        }
#pragma unroll
        for (int nt = 0; nt < 4; nt++) {
            int c = waveN * 64 + nt * 16 + l15;
            short8 bh = *(const short8*)(&Bh[c * LDA + quad * 8]);
            short8 bl = *(const short8*)(&Bl[c * LDA + quad * 8]);
#pragma unroll
            for (int mt = 0; mt < 2; mt++) {
                acc[mt][nt] = __builtin_amdgcn_mfma_f32_16x16x32_bf16(af[mt][0], bh, acc[mt][nt], 0, 0, 0);
                acc[mt][nt] = __builtin_amdgcn_mfma_f32_16x16x32_bf16(af[mt][0], bl, acc[mt][nt], 0, 0, 0);
                acc[mt][nt] = __builtin_amdgcn_mfma_f32_16x16x32_bf16(af[mt][1], bh, acc[mt][nt], 0, 0, 0);
            }
        }
    }

    // ---- transition: h2 tile -> LDS hi/lo ----
    __syncthreads();
    {
        float bs1[4];
#pragma unroll
        for (int nt = 0; nt < 4; nt++) bs1[nt] = b1[waveN * 64 + nt * 16 + l15];
#pragma unroll
        for (int mt = 0; mt < 2; mt++)
#pragma unroll
            for (int nt = 0; nt < 4; nt++)
#pragma unroll
                for (int r = 0; r < 4; r++) {
                    int row = waveM * 32 + mt * 16 + quad * 4 + r;
                    int col = waveN * 64 + nt * 16 + l15;
                    float v = fmaxf(acc[mt][nt][r] + bs1[nt], 0.f);
                    unsigned short h, lo2;
                    split_bf16(v, h, lo2);
                    Hh[row * 136 + col] = h;
                    Hl[row * 136 + col] = lo2;
                }
    }

    // ---- phase 2: K=128, J=96 ----
    floatx4 acc2[2][3];
#pragma unroll
    for (int i = 0; i < 2; i++)
#pragma unroll
        for (int j = 0; j < 3; j++) acc2[i][j] = (floatx4){0.f, 0.f, 0.f, 0.f};

    for (int kt = 0; kt < 128; kt += 32) {
        __syncthreads();
        if (brow < 96) {
            const unsigned short* ph = W2h + (size_t)brow * 128 + kt + bcol;
            const unsigned short* pl = W2l + (size_t)brow * 128 + kt + bcol;
            *(ushort8*)(&B2h[brow * LDA + bcol]) = *(const ushort8*)ph;
            *(ushort8*)(&B2h[brow * LDA + bcol + 8]) = *(const ushort8*)(ph + 8);
            *(ushort8*)(&B2l[brow * LDA + bcol]) = *(const ushort8*)pl;
            *(ushort8*)(&B2l[brow * LDA + bcol + 8]) = *(const ushort8*)(pl + 8);
        }
        __syncthreads();
        short8 af2[2][2];
#pragma unroll
        for (int mt = 0; mt < 2; mt++) {
            int r = waveM * 32 + mt * 16 + l15;
            af2[mt][0] = *(const short8*)(&Hh[r * 136 + kt + quad * 8]);
            af2[mt][1] = *(const short8*)(&Hl[r * 136 + kt + quad * 8]);
        }
#pragma unroll
        for (int nt = 0; nt < 3; nt++) {
            int c = waveN * 48 + nt * 16 + l15;
            short8 bh = *(const short8*)(&B2h[c * LDA + quad * 8]);
            short8 bl = *(const short8*)(&B2l[c * LDA + quad * 8]);
#pragma unroll
            for (int mt = 0; mt < 2; mt++) {
                acc2[mt][nt] = __builtin_amdgcn_mfma_f32_16x16x32_bf16(af2[mt][0], bh, acc2[mt][nt], 0, 0, 0);
                acc2[mt][nt] = __builtin_amdgcn_mfma_f32_16x16x32_bf16(af2[mt][0], bl, acc2[mt][nt], 0, 0, 0);
                acc2[mt][nt] = __builtin_amdgcn_mfma_f32_16x16x32_bf16(af2[mt][1], bh, acc2[mt][nt], 0, 0, 0);
            }
        }
    }

    // ---- epilogue ----
    float bs2[3];
#pragma unroll
    for (int nt = 0; nt < 3; nt++) bs2[nt] = b2[waveN * 48 + nt * 16 + l15];
#pragma unroll
    for (int mt = 0; mt < 2; mt++)
#pragma unroll
        for (int r = 0; r < 4; r++) {
            int grow = m0 + waveM * 32 + mt * 16 + quad * 4 + r;
            if (grow >= M) continue;
#pragma unroll
            for (int nt = 0; nt < 3; nt++) {
                int col = waveN * 48 + nt * 16 + l15;
                C[(size_t)grow * 96 + col] = acc2[mt][nt][r] + bs2[nt];
            }
        }
}

// ================= MFMA decoder =================
__global__ __launch_bounds__(256) void decoder_mfma(
        const float* __restrict__ e0, const float* __restrict__ i1,
        const float* __restrict__ i2, const float* __restrict__ decWt,
        const float* __restrict__ b0, const float* __restrict__ Wout,
        const float* __restrict__ bout, float* __restrict__ out, int N) {
    __shared__ float As[6400];   // [row][k], pitch 100
    __shared__ float Bs[6400];   // [col][k], pitch 100
    __shared__ float red[64][2];
    __shared__ float sb0[64], sWo[64];
    int ch = blockIdx.y;
    int tid = threadIdx.x;
    int m0 = blockIdx.x * 64;

    for (int idx = tid; idx < 1536; idx += 256) {
        int col = idx / 24, k0 = (idx % 24) * 4;
        *(float4*)(&Bs[col * 100 + k0]) = *(const float4*)(decWt + ch * 6144 + col * 96 + k0);
    }
    if (tid < 64) { sb0[tid] = b0[ch * 64 + tid]; sWo[tid] = Wout[ch * 64 + tid]; }
    for (int idx = tid; idx < 1536; idx += 256) {
        int row = idx / 24, k0 = (idx % 24) * 4;
        int m = m0 + row;
        float4 v = {0.f, 0.f, 0.f, 0.f};
        if (m < N) {
            const float* base = (k0 < 32) ? e0 : (k0 < 64 ? i1 : i2);
            v = *(const float4*)(base + (size_t)m * 96 + ch * 32 + (k0 & 31));
        }
        *(float4*)(&As[row * 100 + k0]) = v;
    }
    __syncthreads();

    int lane = tid & 63, wid = tid >> 6;
    int waveM = wid & 1, waveN = wid >> 1;
    int l15 = lane & 15, quad = lane >> 4;
    floatx4 acc[2][2];
#pragma unroll
    for (int i = 0; i < 2; i++)
#pragma unroll
        for (int j = 0; j < 2; j++) acc[i][j] = (floatx4){0.f, 0.f, 0.f, 0.f};

#pragma unroll
    for (int kt = 0; kt < 96; kt += 32) {
        short8 ah[2], al[2];
#pragma unroll
        for (int mt = 0; mt < 2; mt++) {
            int r = waveM * 32 + mt * 16 + l15;
            split8(&As[r * 100 + kt + quad * 8], ah[mt], al[mt]);
        }
#pragma unroll
        for (int nt = 0; nt < 2; nt++) {
            int c = waveN * 32 + nt * 16 + l15;
            short8 bh, bl;
            split8(&Bs[c * 100 + kt + quad * 8], bh, bl);
#pragma unroll
            for (int mt = 0; mt < 2; mt++) {
                acc[mt][nt] = __builtin_amdgcn_mfma_f32_16x16x32_bf16(ah[mt], bh, acc[mt][nt], 0, 0, 0);
                acc[mt][nt] = __builtin_amdgcn_mfma_f32_16x16x32_bf16(ah[mt], bl, acc[mt][nt], 0, 0, 0);
                acc[mt][nt] = __builtin_amdgcn_mfma_f32_16x16x32_bf16(al[mt], bh, acc[mt][nt], 0, 0, 0);
            }
        }
    }

    float cb0[2], cwo[2];
#pragma unroll
    for (int nt = 0; nt < 2; nt++) {
        int col = waveN * 32 + nt * 16 + l15;
        cb0[nt] = sb0[col]; cwo[nt] = sWo[col];
    }
    float p[2][4];
#pragma unroll
    for (int mt = 0; mt < 2; mt++)
#pragma unroll
        for (int r = 0; r < 4; r++) {
            float s = 0.f;
#pragma unroll
            for (int nt = 0; nt < 2; nt++) {
                float h = acc[mt][nt][r] + cb0[nt];
                h = h > 0.f ? h : (expf(h) - 1.0f);
                s += h * cwo[nt];
            }
            p[mt][r] = s;
        }
#pragma unroll
    for (int mt = 0; mt < 2; mt++)
#pragma unroll
        for (int r = 0; r < 4; r++) {
#pragma unroll
            for (int msk = 1; msk < 16; msk <<= 1)
                p[mt][r] += __shfl_xor(p[mt][r], msk, 64);
        }
    if (l15 == 0) {
#pragma unroll
        for (int mt = 0; mt < 2; mt++)
#pragma unroll
            for (int r = 0; r < 4; r++) {
                int row = waveM * 32 + mt * 16 + quad * 4 + r;
                red[row][waveN] = p[mt][r];
            }
    }
    __syncthreads();
    if (tid < 64) {
        int m = m0 + tid;
        if (m < N) out[(size_t)m * 3 + ch] = red[tid][0] + red[tid][1] + bout[ch];
    }
}

// ================= host launch =================

extern "C" void kernel_launch(void* const* d_in, const int* in_sizes, int n_in,
                              void* d_out, int out_size, void* d_ws, size_t ws_size,
                              hipStream_t stream) {
    const float* x0 = (const float*)d_in[0];
    const float* x1 = (const float*)d_in[1];
    const float* x2 = (const float*)d_in[2];
    const int* ei0 = (const int*)d_in[3];
    const int* ei1 = (const int*)d_in[4];
    const int* ei2 = (const int*)d_in[5];
    const int* A1r = (const int*)d_in[6];
    const int* A1c = (const int*)d_in[7];
    const float* A1v = (const float*)d_in[8];
    const int* A2r = (const int*)d_in[9];
    const int* A2c = (const int*)d_in[10];
    const float* A2v = (const float*)d_in[11];
    const float* c1Wrel = (const float*)d_in[12];
    const float* c1brel = (const float*)d_in[13];
    const float* c1Wroot = (const float*)d_in[14];
    const float* c2Wrel = (const float*)d_in[15];
    const float* c2brel = (const float*)d_in[16];
    const float* c2Wroot = (const float*)d_in[17];
    const float* linW = (const float*)d_in[18];
    const float* linb = (const float*)d_in[19];
    const float* dW0 = (const float*)d_in[20];
    const float* db0 = (const float*)d_in[21];
    const float* dWout = (const float*)d_in[22];
    const float* dbout = (const float*)d_in[23];
    float* out = (float*)d_out;

    // ---- workspace (float words) ----
    float* ws = (float*)d_ws;
    unsigned short* h1hi = (unsigned short*)(ws + 400000);   // node-major, 8.4M ushorts
    unsigned short* h1lo = (unsigned short*)(ws + 4600000);  // node-major, 8.4M ushorts
    float* aggH = ws + 8800000;                  // 8.4M words [8.8M, 17.2M)
    float* ecat = ws + 17200000;                 // 6.3M words
    // binned intermediates overlay aggH (dead before gatherH writes aggH)
    int* bpacked = (int*)(ws + 8800000);         // 1,450,000
    float* bval = ws + 8800000 + 1450000;        // 1,450,000 (ends 11.7M < 17.2M)
    float* i1 = aggH;                            // overlay (dead after conv2lin)
    float* i2 = ws + 400000;                     // overlays h1 planes (dead after conv2lin)
    int* hist_g = (int*)(ws + 23500000);         // NBUCK*NBLK = 115,020
    int* btot = (int*)(ws + 23615020);           // 325
    int* bbase = (int*)(ws + 23615344);          // 325
    int* offs = (int*)(ws + 23665632);           // 165,626
    int* csrc = (int*)(ws + 23831264);           // 1,450,000
    float* cval = ws + 25281392;                 // 400,000
    unsigned short* c2hi = (unsigned short*)(ws + 25681392); // 98,304 ushort
    unsigned short* c2lo = c2hi + 98304;
    unsigned short* lnhi = c2lo + 98304;                     // 36,864 ushort
    unsigned short* lnlo = lnhi + 36864;
    float* decWt = ws + 25681392 + 135168;       // 18,432 floats; ends ~25,834,992 (~103.3 MB)

    conv_weights<<<(153600 + 255) / 256, 256, 0, stream>>>(
        c2Wrel, c2Wroot, linW, dW0, c2hi, c2lo, lnhi, lnlo, decWt, btot);

    // ---- binned CSR build ----
    bin_hist<<<NBLK, 256, 0, stream>>>(ei0, ei1, ei2, A1r, A2r, hist_g, btot);
    hist_scan<<<NBUCK, 64, 0, stream>>>(hist_g, btot, bbase);
    bin_scatter<<<NBLK, 256, 0, stream>>>(ei0, ei1, ei2, A1r, A1c, A1v,
                                          A2r, A2c, A2v, hist_g, bpacked, bval);
    bucket_fill<<<NBUCK, 256, 0, stream>>>(bpacked, bval, bbase, offs, csrc, cval);

    // ---- encoder ----
    dim3 g1(1027, 2);
    conv1_b<<<g1, 256, 0, stream>>>(offs, csrc, x0, x1, x2,
                                    c1Wrel, c1Wroot, c1brel, h1hi, h1lo);
    gatherH_b<<<((size_t)NT * 16 + 255) / 256, 256, 0, stream>>>(h1hi, offs, csrc, aggH);
    conv2lin<<<1027, 256, 0, stream>>>(aggH, h1hi, h1lo, c2hi, c2lo, c2brel,
                                       lnhi, lnlo, linb, ecat);

    // ---- interpolation (i1 over aggH, i2 over h1 planes — both dead now) ----
    interp_b<<<((size_t)2 * N0 * 24 + 255) / 256, 256, 0, stream>>>(
        ecat, offs, csrc, cval, i1, i2);

    // ---- decoder ----
    dim3 gd(782, 3);
    decoder_mfma<<<gd, 256, 0, stream>>>(ecat, i1, i2, decWt, db0, dWout, dbout, out, N0);
}

// Round 15
// 298.394 us; speedup vs baseline: 1.2249x; 1.0271x over previous
//
#include <hip/hip_runtime.h>
#include <math.h>

#define N0 50000
#define N1 12500
#define N2 3125
#define NNZ 200000
#define NE0 800000
#define NE1 200000
#define NE2 50000
#define NT 65625           // N0+N1+N2
#define SEG_TOT 165625     // NT + 2*N0
#define EDGE_TOT 1050000   // NE0+NE1+NE2
#define ITEM_TOT 1450000   // EDGE_TOT + 2*NNZ
#define NBUCK 324          // ceil(SEG_TOT/512)
#define SPB 512            // segs per bucket
#define NBLK 355           // ceil(ITEM_TOT/4096)

typedef __attribute__((ext_vector_type(8))) short short8;
typedef __attribute__((ext_vector_type(8))) unsigned short ushort8;
typedef __attribute__((ext_vector_type(4))) float floatx4;

__device__ inline void split_bf16(float x, unsigned short& hi, unsigned short& lo) {
    unsigned xb = __float_as_uint(x);
    hi = (unsigned short)(xb >> 16);
    float hf = __uint_as_float((unsigned)hi << 16);
    lo = (unsigned short)(__float_as_uint(x - hf) >> 16);
}

__device__ inline unsigned short bf16_rne(float x) {
    unsigned xb = __float_as_uint(x);
    return (unsigned short)((xb + 0x7fff + ((xb >> 16) & 1)) >> 16);
}

// split 8 contiguous fp32 (LDS) into hi/lo bf16 frags
__device__ inline void split8(const float* p, short8& hi, short8& lo) {
    float4 u0 = *(const float4*)p;
    float4 u1 = *(const float4*)(p + 4);
    float f[8] = {u0.x, u0.y, u0.z, u0.w, u1.x, u1.y, u1.z, u1.w};
#pragma unroll
    for (int j = 0; j < 8; j++) {
        unsigned short h, l;
        split_bf16(f[j], h, l);
        hi[j] = (short)h; lo[j] = (short)l;
    }
}

// ================= binned CSR build =================
// seg space: [0,50000) L0 nodes, [50000,62500) L1, [62500,65625) L2,
// [65625,115625) interp1 rows, [115625,165625) interp2 rows.

__device__ inline int item_seg(int t, const int* __restrict__ ei0,
                               const int* __restrict__ ei1, const int* __restrict__ ei2,
                               const int* __restrict__ A1r, const int* __restrict__ A2r) {
    if (t < NE0) return ei0[NE0 + t];
    if (t < NE0 + NE1) return 50000 + ei1[NE1 + (t - NE0)];
    if (t < EDGE_TOT) return 62500 + ei2[NE2 + (t - (NE0 + NE1))];
    if (t < EDGE_TOT + NNZ) return NT + A1r[t - EDGE_TOT];
    return NT + N0 + A2r[t - (EDGE_TOT + NNZ)];
}

// A: per-block bucket histogram -> hist_g[bucket*NBLK + blk]; also bucket totals
__global__ __launch_bounds__(256) void bin_hist(const int* __restrict__ ei0,
        const int* __restrict__ ei1, const int* __restrict__ ei2,
        const int* __restrict__ A1r, const int* __restrict__ A2r,
        int* __restrict__ hist_g, int* __restrict__ btot) {
    __shared__ int h[NBUCK];
    for (int i = threadIdx.x; i < NBUCK; i += 256) h[i] = 0;
    __syncthreads();
    int base = blockIdx.x * 4096;
#pragma unroll
    for (int q = 0; q < 16; q++) {
        int t = base + q * 256 + threadIdx.x;
        if (t < ITEM_TOT) atomicAdd(&h[item_seg(t, ei0, ei1, ei2, A1r, A2r) >> 9], 1);
    }
    __syncthreads();
    for (int i = threadIdx.x; i < NBUCK; i += 256) {
        int v = h[i];
        hist_g[i * NBLK + blockIdx.x] = v;
        if (v) atomicAdd(&btot[i], v);
    }
}

// B3: per-bucket exclusive scan of hist_g row + bucket_base
__global__ void hist_scan(int* __restrict__ hist_g, const int* __restrict__ btot,
                          int* __restrict__ bbase) {
    int b = blockIdx.x, lane = threadIdx.x;
    int s = 0;
    for (int j = lane; j < b; j += 64) s += btot[j];
#pragma unroll
    for (int o = 32; o > 0; o >>= 1) s += __shfl_down(s, o, 64);
    int base = __shfl(s, 0, 64);
    if (lane == 0) {
        bbase[b] = base;
        if (b == NBUCK - 1) bbase[NBUCK] = ITEM_TOT;
    }
    int v[6], ts = 0;
#pragma unroll
    for (int q = 0; q < 6; q++) {
        int i = lane * 6 + q;
        v[q] = (i < NBLK) ? hist_g[b * NBLK + i] : 0;
        ts += v[q];
    }
    int sc = ts;
#pragma unroll
    for (int o = 1; o < 64; o <<= 1) {
        int t2 = __shfl_up(sc, o, 64);
        if (lane >= o) sc += t2;
    }
    int run = base + sc - ts;
#pragma unroll
    for (int q = 0; q < 6; q++) {
        int i = lane * 6 + q;
        if (i < NBLK) hist_g[b * NBLK + i] = run;
        run += v[q];
    }
}

// C: scatter items into bucket-ordered packed array
__global__ __launch_bounds__(256) void bin_scatter(const int* __restrict__ ei0,
        const int* __restrict__ ei1, const int* __restrict__ ei2,
        const int* __restrict__ A1r, const int* __restrict__ A1c, const float* __restrict__ A1v,
        const int* __restrict__ A2r, const int* __restrict__ A2c, const float* __restrict__ A2v,
        const int* __restrict__ hist_g, int* __restrict__ bpacked, float* __restrict__ bval) {
    __shared__ int cur[NBUCK];
    for (int i = threadIdx.x; i < NBUCK; i += 256) cur[i] = hist_g[i * NBLK + blockIdx.x];
    __syncthreads();
    int base = blockIdx.x * 4096;
#pragma unroll
    for (int q = 0; q < 16; q++) {
        int t = base + q * 256 + threadIdx.x;
        if (t >= ITEM_TOT) continue;
        int seg, pay;
        float val = 0.f;
        bool isv = false;
        if (t < NE0) { seg = ei0[NE0 + t]; pay = ei0[t]; }
        else if (t < NE0 + NE1) { int e = t - NE0; seg = 50000 + ei1[NE1 + e]; pay = ei1[e]; }
        else if (t < EDGE_TOT) { int e = t - (NE0 + NE1); seg = 62500 + ei2[NE2 + e]; pay = ei2[e]; }
        else if (t < EDGE_TOT + NNZ) { int k = t - EDGE_TOT; seg = NT + A1r[k]; pay = A1c[k]; val = A1v[k]; isv = true; }
        else { int k = t - (EDGE_TOT + NNZ); seg = NT + N0 + A2r[k]; pay = A2c[k]; val = A2v[k]; isv = true; }
        int bk = seg >> 9;
        int p = atomicAdd(&cur[bk], 1);
        bpacked[p] = ((seg - (bk << 9)) << 16) | pay;  // seg_local<512, pay<65536
        if (isv) bval[p] = val;
    }
}

// E: per-bucket count + scan + fill; writes offs[seg]=start directly.
__global__ __launch_bounds__(256) void bucket_fill(const int* __restrict__ bpacked,
        const float* __restrict__ bval, const int* __restrict__ bbase,
        int* __restrict__ offs, int* __restrict__ csrc, float* __restrict__ cval) {
    __shared__ int cnt[SPB];
    __shared__ int wsum2[4];
    int b = blockIdx.x, tid = threadIdx.x;
    int segbase = b * SPB;
    int seglim = SEG_TOT - segbase;
    if (seglim > SPB) seglim = SPB;
    int ibeg = bbase[b], iend = bbase[b + 1];
    for (int i = tid; i < SPB; i += 256) cnt[i] = 0;
    __syncthreads();
    for (int i = ibeg + tid; i < iend; i += 256)
        atomicAdd(&cnt[bpacked[i] >> 16], 1);
    __syncthreads();
    int lane = tid & 63, wid = tid >> 6;
    int v0 = cnt[tid * 2], v1 = cnt[tid * 2 + 1];
    int ts = v0 + v1, sc = ts;
#pragma unroll
    for (int o = 1; o < 64; o <<= 1) {
        int t2 = __shfl_up(sc, o, 64);
        if (lane >= o) sc += t2;
    }
    if (lane == 63) wsum2[wid] = sc;
    __syncthreads();
    int woff = 0;
    for (int w = 0; w < wid; w++) woff += wsum2[w];
    int ex = ibeg + woff + sc - ts;  // start position of seg tid*2
    __syncthreads();
    cnt[tid * 2] = ex;
    cnt[tid * 2 + 1] = ex + v0;
    if (tid * 2 < seglim) offs[segbase + tid * 2] = ex;
    if (tid * 2 + 1 < seglim) offs[segbase + tid * 2 + 1] = ex + v0;
    if (b == NBUCK - 1 && tid == 0) offs[SEG_TOT] = ITEM_TOT;
    __syncthreads();
    for (int i = ibeg + tid; i < iend; i += 256) {
        int w2 = bpacked[i];
        int sl = w2 >> 16, pay = w2 & 0xffff;
        int p = atomicAdd(&cnt[sl], 1);
        csrc[p] = pay;
        if (segbase + sl >= NT) cval[p - EDGE_TOT] = bval[i];
    }
}

// ================= batched gathers =================
// segment n spans [offs[n], offs[n+1])

__device__ inline void acc_u4(uint4 u, float* a) {
    a[0] += __uint_as_float(u.x << 16);
    a[1] += __uint_as_float(u.x & 0xffff0000u);
    a[2] += __uint_as_float(u.y << 16);
    a[3] += __uint_as_float(u.y & 0xffff0000u);
    a[4] += __uint_as_float(u.z << 16);
    a[5] += __uint_as_float(u.z & 0xffff0000u);
    a[6] += __uint_as_float(u.w << 16);
    a[7] += __uint_as_float(u.w & 0xffff0000u);
}

// node-major bf16 hi plane; 16 lanes/node x uint4 (8 feats), edge loop unrolled x4.
// Output agg is bf16-RNE (hi only): halves write traffic; consumer splits no more.
__global__ __launch_bounds__(256) void gatherH_b(const unsigned short* __restrict__ h1hi,
                                                 const int* __restrict__ offs,
                                                 const int* __restrict__ csrc,
                                                 unsigned short* __restrict__ aggh) {
    int t = blockIdx.x * blockDim.x + threadIdx.x;
    int n = t >> 4, g = t & 15;
    if (n >= NT) return;
    int nb = (n < 50000) ? 0 : (n < 62500 ? 50000 : 62500);
    float a[8] = {};
    int b = offs[n], e = offs[n + 1];
    int j = b;
    for (; j + 3 < e; j += 4) {
        int s0 = csrc[j], s1 = csrc[j + 1], s2 = csrc[j + 2], s3 = csrc[j + 3];
        uint4 u0 = *(const uint4*)(h1hi + (size_t)(nb + s0) * 128 + g * 8);
        uint4 u1 = *(const uint4*)(h1hi + (size_t)(nb + s1) * 128 + g * 8);
        uint4 u2 = *(const uint4*)(h1hi + (size_t)(nb + s2) * 128 + g * 8);
        uint4 u3 = *(const uint4*)(h1hi + (size_t)(nb + s3) * 128 + g * 8);
        acc_u4(u0, a);
        acc_u4(u1, a);
        acc_u4(u2, a);
        acc_u4(u3, a);
    }
    for (; j < e; j++) {
        uint4 u0 = *(const uint4*)(h1hi + (size_t)(nb + csrc[j]) * 128 + g * 8);
        acc_u4(u0, a);
    }
    ushort8 o;
#pragma unroll
    for (int q = 0; q < 8; q++) o[q] = bf16_rne(a[q]);
    *(ushort8*)(aggh + (size_t)n * 128 + g * 8) = o;
}

// interp: 24 threads/node, edge loop unrolled x2 for MLP
__global__ __launch_bounds__(256) void interp_b(const float* __restrict__ ecat,
                                                const int* __restrict__ offs,
                                                const int* __restrict__ csrc,
                                                const float* __restrict__ cval,
                                                float* __restrict__ i1, float* __restrict__ i2) {
    int t = blockIdx.x * blockDim.x + threadIdx.x;
    int ng = t / 24, g = t % 24;
    if (ng >= 2 * N0) return;
    int a = (ng >= N0) ? 1 : 0;
    int nl = ng - a * N0;
    const float* e = ecat + (size_t)(a ? 62500 : 50000) * 96;
    float* ob = a ? i2 : i1;
    int seg = NT + ng;
    float4 s = {0.f, 0.f, 0.f, 0.f};
    int b = offs[seg], en = offs[seg + 1];
    int j = b;
    for (; j + 1 < en; j += 2) {
        int c0 = csrc[j], c1 = csrc[j + 1];
        float v0 = cval[j - EDGE_TOT], v1 = cval[j + 1 - EDGE_TOT];
        float4 w0 = ((const float4*)(e + (size_t)c0 * 96))[g];
        float4 w1 = ((const float4*)(e + (size_t)c1 * 96))[g];
        s.x += v0 * w0.x + v1 * w1.x;
        s.y += v0 * w0.y + v1 * w1.y;
        s.z += v0 * w0.z + v1 * w1.z;
        s.w += v0 * w0.w + v1 * w1.w;
    }
    if (j < en) {
        int c0 = csrc[j];
        float v0 = cval[j - EDGE_TOT];
        float4 w0 = ((const float4*)(e + (size_t)c0 * 96))[g];
        s.x += v0 * w0.x; s.y += v0 * w0.y; s.z += v0 * w0.z; s.w += v0 * w0.w;
    }
    ((float4*)(ob + (size_t)nl * 96))[g] = s;
}

// ================= weight preconvert (also zeroes btot) =================
__global__ void conv_weights(const float* __restrict__ c2Wrel, const float* __restrict__ c2Wroot,
                             const float* __restrict__ linW, const float* __restrict__ dW0,
                             unsigned short* __restrict__ c2hi, unsigned short* __restrict__ c2lo,
                             unsigned short* __restrict__ lhi, unsigned short* __restrict__ llo,
                             float* __restrict__ decWt, int* __restrict__ btot) {
    int t = blockIdx.x * blockDim.x + threadIdx.x;
    if (t <= NBUCK) btot[t] = 0;
    if (t < 98304) {
        int i = t / 32768, r = t % 32768;
        int n = r / 256, k = r % 256;
        float w = (k < 128) ? c2Wrel[i * 16384 + k * 128 + n]
                            : c2Wroot[i * 16384 + (k - 128) * 128 + n];
        unsigned short hi, lo;
        split_bf16(w, hi, lo);
        c2hi[t] = hi; c2lo[t] = lo;
    } else if (t < 135168) {
        int u = t - 98304;
        int i = u / 12288, r = u % 12288;
        int n = r / 128, k = r % 128;
        unsigned short hi, lo;
        split_bf16(linW[i * 12288 + k * 96 + n], hi, lo);
        lhi[u] = hi; llo[u] = lo;
    } else if (t < 153600) {
        int u = t - 135168;
        int chn = u / 6144, r = u % 6144;
        int col = r / 96, k = r % 96;
        decWt[u] = dW0[chn * 6144 + k * 64 + col];
    }
}

// ===== conv1 (fp32, K=12, 64x128 single-pass) with fused CSR gather =====
__global__ __launch_bounds__(256) void conv1_b(
        const int* __restrict__ offs, const int* __restrict__ csrc,
        const float* __restrict__ x0, const float* __restrict__ x1,
        const float* __restrict__ x2,
        const float* __restrict__ Wrel, const float* __restrict__ Wroot,
        const float* __restrict__ brel,
        unsigned short* __restrict__ h1hi, unsigned short* __restrict__ h1lo) {
    __shared__ float As[12][65];
    __shared__ float Ws[12][128];
    int bx = blockIdx.x;
    int l, lbk;
    if (bx < 782) { l = 0; lbk = bx; }
    else if (bx < 978) { l = 1; lbk = bx - 782; }
    else { l = 2; lbk = bx - 978; }
    int nb = (l == 0) ? 0 : (l == 1 ? 50000 : 62500);
    int M = (l == 0) ? N0 : (l == 1 ? N1 : N2);
    const float* xl = (l == 0) ? x0 : (l == 1 ? x1 : x2);
    const float* W1 = Wrel + l * 768;
    const float* W2 = Wroot + l * 768;
    const float* bias = brel + l * 128;
    int m0 = lbk * 64;
    int tid = threadIdx.x;

    // fused gather: 4 threads/row compute segment partials, shfl-reduce (once per row)
    {
        int row = tid >> 2, sub = tid & 3;
        int m = m0 + row;
        float a6[6] = {};
        if (m < M) {
            int jb = offs[nb + m], je = offs[nb + m + 1];
            for (int j = jb + sub; j < je; j += 4) {
                const float* p = xl + (size_t)csrc[j] * 6;
                a6[0] += p[0]; a6[1] += p[1]; a6[2] += p[2];
                a6[3] += p[3]; a6[4] += p[4]; a6[5] += p[5];
            }
        }
#pragma unroll
        for (int msk = 1; msk < 4; msk <<= 1) {
#pragma unroll
            for (int q = 0; q < 6; q++) a6[q] += __shfl_xor(a6[q], msk, 64);
        }
        if (sub == 0) {
#pragma unroll
            for (int q = 0; q < 6; q++) As[q][row] = (m < M) ? a6[q] : 0.f;
        } else if (sub == 1) {
#pragma unroll
            for (int q = 0; q < 6; q++)
                As[6 + q][row] = (m < M) ? xl[(size_t)m * 6 + q] : 0.f;
        }
    }
    // W staging (12 x 128)
    for (int idx = tid; idx < 1536; idx += 256) {
        int kk = idx >> 7, nn2 = idx & 127;
        Ws[kk][nn2] = (kk < 6) ? W1[kk * 128 + nn2] : W2[(kk - 6) * 128 + nn2];
    }
    __syncthreads();

    int tm = tid >> 4, tn = tid & 15;  // tm: 4-row group, tn: handles cols tn*4 and 64+tn*4
    float acc[4][8] = {};
#pragma unroll
    for (int k = 0; k < 12; k++) {
        float av[4], wv[8];
#pragma unroll
        for (int i = 0; i < 4; i++) av[i] = As[k][tm * 4 + i];
#pragma unroll
        for (int j = 0; j < 4; j++) { wv[j] = Ws[k][tn * 4 + j]; wv[4 + j] = Ws[k][64 + tn * 4 + j]; }
#pragma unroll
        for (int i = 0; i < 4; i++)
#pragma unroll
            for (int j = 0; j < 8; j++) acc[i][j] += av[i] * wv[j];
    }
#pragma unroll
    for (int i = 0; i < 4; i++) {
        int m = m0 + tm * 4 + i;
        if (m >= M) continue;
#pragma unroll
        for (int half = 0; half < 2; half++) {
            int c0 = half * 64 + tn * 4;
            unsigned short hs[4], ls[4];
#pragma unroll
            for (int j = 0; j < 4; j++) {
                float v = fmaxf(acc[i][half * 4 + j] + bias[c0 + j], 0.f);
                split_bf16(v, hs[j], ls[j]);
            }
            uint2 ph = {(unsigned)hs[0] | ((unsigned)hs[1] << 16),
                        (unsigned)hs[2] | ((unsigned)hs[3] << 16)};
            uint2 pl = {(unsigned)ls[0] | ((unsigned)ls[1] << 16),
                        (unsigned)ls[2] | ((unsigned)ls[3] << 16)};
            size_t off = (size_t)(nb + m) * 128 + c0;
            *(uint2*)(h1hi + off) = ph;
            *(uint2*)(h1lo + off) = pl;
        }
    }
}

// ================= fused conv2+lin (split-bf16 MFMA) =================
// A-tile: kt<128 -> bf16 agg (hi only, lo==0); kt>=128 -> pre-split h1 planes.
__global__ __launch_bounds__(256) void conv2lin(
        const unsigned short* __restrict__ aggh,
        const unsigned short* __restrict__ h1hi, const unsigned short* __restrict__ h1lo,
        const unsigned short* __restrict__ c2hi, const unsigned short* __restrict__ c2lo,
        const float* __restrict__ c2b,
        const unsigned short* __restrict__ lnhi, const unsigned short* __restrict__ lnlo,
        const float* __restrict__ lnb, float* __restrict__ ecat) {
    __shared__ unsigned short smem[25088];  // 50.2 KB union
    unsigned short* Ah = smem;              // 64*40
    unsigned short* Al = smem + 2560;
    unsigned short* Bh = smem + 5120;       // 128*40
    unsigned short* Bl = smem + 10240;
    unsigned short* Hh = smem;              // 64*136 (phase 2)
    unsigned short* Hl = smem + 8704;
    unsigned short* B2h = smem + 17408;     // 96*40
    unsigned short* B2l = smem + 21248;
    const int LDA = 40;

    int bx = blockIdx.x;
    int l, lbk;
    if (bx < 782) { l = 0; lbk = bx; }
    else if (bx < 978) { l = 1; lbk = bx - 782; }
    else { l = 2; lbk = bx - 978; }
    int nb = (l == 0) ? 0 : (l == 1 ? 50000 : 62500);
    int M = (l == 0) ? N0 : (l == 1 ? N1 : N2);
    const unsigned short* A1h = aggh + (size_t)nb * 128;
    const unsigned short* A2h = h1hi + (size_t)nb * 128;
    const unsigned short* A2l = h1lo + (size_t)nb * 128;
    const unsigned short* W1h = c2hi + l * 32768;
    const unsigned short* W1l = c2lo + l * 32768;
    const float* b1 = c2b + l * 128;
    const unsigned short* W2h = lnhi + l * 12288;
    const unsigned short* W2l = lnlo + l * 12288;
    const float* b2 = lnb + l * 96;
    float* C = ecat + (size_t)nb * 96;
    int m0 = lbk * 64;

    int tid = threadIdx.x;
    int lane = tid & 63, wid = tid >> 6;
    int waveM = wid & 1, waveN = wid >> 1;
    int l15 = lane & 15, quad = lane >> 4;
    int arow = tid >> 2, acol = (tid & 3) * 8;
    int brow = tid >> 1, bcol = (tid & 1) * 16;

    floatx4 acc[2][4];
#pragma unroll
    for (int i = 0; i < 2; i++)
#pragma unroll
        for (int j = 0; j < 4; j++) acc[i][j] = (floatx4){0.f, 0.f, 0.f, 0.f};

    // ---- phase 1: K=256 ----
    for (int kt = 0; kt < 256; kt += 32) {
        bool hasLo = (kt >= 128);  // agg part has no lo plane
        __syncthreads();
        {
            int m = m0 + arow;
            ushort8 hv = (ushort8)0, lv = (ushort8)0;
            if (m < M) {
                int kg = kt + acol;
                if (!hasLo) {
                    hv = *(const ushort8*)(A1h + (size_t)m * 128 + kg);
                } else {
                    size_t off = (size_t)m * 128 + (kg - 128);
                    hv = *(const ushort8*)(A2h + off);
                    lv = *(const ushort8*)(A2l + off);
                }
            }
            *(ushort8*)(&Ah[arow * LDA + acol]) = hv;
            if (hasLo) *(ushort8*)(&Al[arow * LDA + acol]) = lv;
        }
        {
            const unsigned short* ph = W1h + (size_t)brow * 256 + kt + bcol;
            const unsigned short* pl = W1l + (size_t)brow * 256 + kt + bcol;
            *(ushort8*)(&Bh[brow * LDA + bcol]) = *(const ushort8*)ph;
            *(ushort8*)(&Bh[brow * LDA + bcol + 8]) = *(const ushort8*)(ph + 8);
            *(ushort8*)(&Bl[brow * LDA + bcol]) = *(const ushort8*)pl;
            *(ushort8*)(&Bl[brow * LDA + bcol + 8]) = *(const ushort8*)(pl + 8);
        }
        __syncthreads();
        short8 af[2][2];
#pragma unroll
        for (int mt = 0; mt < 2; mt++) {
            int r = waveM * 32 + mt * 16 + l15;
            af[mt][0] = *(const short8*)(&Ah[r * LDA + quad * 8]);
            if (hasLo) af[mt][1] = *(const short8*)(&Al[r * LDA + quad * 8]);
        }
#pragma unroll
        for (int nt = 0; nt < 4; nt++) {
            int c = waveN * 64 + nt * 16 + l15;
            short8 bh = *(const short8*)(&Bh[c * LDA + quad * 8]);
            short8 bl = *(const short8*)(&Bl[c * LDA + quad * 8]);
#pragma unroll
            for (int mt = 0; mt < 2; mt++) {
                acc[mt][nt] = __builtin_amdgcn_mfma_f32_16x16x32_bf16(af[mt][0], bh, acc[mt][nt], 0, 0, 0);
                acc[mt][nt] = __builtin_amdgcn_mfma_f32_16x16x32_bf16(af[mt][0], bl, acc[mt][nt], 0, 0, 0);
                if (hasLo)
                    acc[mt][nt] = __builtin_amdgcn_mfma_f32_16x16x32_bf16(af[mt][1], bh, acc[mt][nt], 0, 0, 0);
            }
        }
    }

    // ---- transition: h2 tile -> LDS hi/lo ----
    __syncthreads();
    {
        float bs1[4];
#pragma unroll
        for (int nt = 0; nt < 4; nt++) bs1[nt] = b1[waveN * 64 + nt * 16 + l15];
#pragma unroll
        for (int mt = 0; mt < 2; mt++)
#pragma unroll
            for (int nt = 0; nt < 4; nt++)
#pragma unroll
                for (int r = 0; r < 4; r++) {
                    int row = waveM * 32 + mt * 16 + quad * 4 + r;
                    int col = waveN * 64 + nt * 16 + l15;
                    float v = fmaxf(acc[mt][nt][r] + bs1[nt], 0.f);
                    unsigned short h, lo2;
                    split_bf16(v, h, lo2);
                    Hh[row * 136 + col] = h;
                    Hl[row * 136 + col] = lo2;
                }
    }

    // ---- phase 2: K=128, J=96 ----
    floatx4 acc2[2][3];
#pragma unroll
    for (int i = 0; i < 2; i++)
#pragma unroll
        for (int j = 0; j < 3; j++) acc2[i][j] = (floatx4){0.f, 0.f, 0.f, 0.f};

    for (int kt = 0; kt < 128; kt += 32) {
        __syncthreads();
        if (brow < 96) {
            const unsigned short* ph = W2h + (size_t)brow * 128 + kt + bcol;
            const unsigned short* pl = W2l + (size_t)brow * 128 + kt + bcol;
            *(ushort8*)(&B2h[brow * LDA + bcol]) = *(const ushort8*)ph;
            *(ushort8*)(&B2h[brow * LDA + bcol + 8]) = *(const ushort8*)(ph + 8);
            *(ushort8*)(&B2l[brow * LDA + bcol]) = *(const ushort8*)pl;
            *(ushort8*)(&B2l[brow * LDA + bcol + 8]) = *(const ushort8*)(pl + 8);
        }
        __syncthreads();
        short8 af2[2][2];
#pragma unroll
        for (int mt = 0; mt < 2; mt++) {
            int r = waveM * 32 + mt * 16 + l15;
            af2[mt][0] = *(const short8*)(&Hh[r * 136 + kt + quad * 8]);
            af2[mt][1] = *(const short8*)(&Hl[r * 136 + kt + quad * 8]);
        }
#pragma unroll
        for (int nt = 0; nt < 3; nt++) {
            int c = waveN * 48 + nt * 16 + l15;
            short8 bh = *(const short8*)(&B2h[c * LDA + quad * 8]);
            short8 bl = *(const short8*)(&B2l[c * LDA + quad * 8]);
#pragma unroll
            for (int mt = 0; mt < 2; mt++) {
                acc2[mt][nt] = __builtin_amdgcn_mfma_f32_16x16x32_bf16(af2[mt][0], bh, acc2[mt][nt], 0, 0, 0);
                acc2[mt][nt] = __builtin_amdgcn_mfma_f32_16x16x32_bf16(af2[mt][0], bl, acc2[mt][nt], 0, 0, 0);
                acc2[mt][nt] = __builtin_amdgcn_mfma_f32_16x16x32_bf16(af2[mt][1], bh, acc2[mt][nt], 0, 0, 0);
            }
        }
    }

    // ---- epilogue ----
    float bs2[3];
#pragma unroll
    for (int nt = 0; nt < 3; nt++) bs2[nt] = b2[waveN * 48 + nt * 16 + l15];
#pragma unroll
    for (int mt = 0; mt < 2; mt++)
#pragma unroll
        for (int r = 0; r < 4; r++) {
            int grow = m0 + waveM * 32 + mt * 16 + quad * 4 + r;
            if (grow >= M) continue;
#pragma unroll
            for (int nt = 0; nt < 3; nt++) {
                int col = waveN * 48 + nt * 16 + l15;
                C[(size_t)grow * 96 + col] = acc2[mt][nt][r] + bs2[nt];
            }
        }
}

// ================= MFMA decoder =================
__global__ __launch_bounds__(256) void decoder_mfma(
        const float* __restrict__ e0, const float* __restrict__ i1,
        const float* __restrict__ i2, const float* __restrict__ decWt,
        const float* __restrict__ b0, const float* __restrict__ Wout,
        const float* __restrict__ bout, float* __restrict__ out, int N) {
    __shared__ float As[6400];   // [row][k], pitch 100
    __shared__ float Bs[6400];   // [col][k], pitch 100
    __shared__ float red[64][2];
    __shared__ float sb0[64], sWo[64];
    int ch = blockIdx.y;
    int tid = threadIdx.x;
    int m0 = blockIdx.x * 64;

    for (int idx = tid; idx < 1536; idx += 256) {
        int col = idx / 24, k0 = (idx % 24) * 4;
        *(float4*)(&Bs[col * 100 + k0]) = *(const float4*)(decWt + ch * 6144 + col * 96 + k0);
    }
    if (tid < 64) { sb0[tid] = b0[ch * 64 + tid]; sWo[tid] = Wout[ch * 64 + tid]; }
    for (int idx = tid; idx < 1536; idx += 256) {
        int row = idx / 24, k0 = (idx % 24) * 4;
        int m = m0 + row;
        float4 v = {0.f, 0.f, 0.f, 0.f};
        if (m < N) {
            const float* base = (k0 < 32) ? e0 : (k0 < 64 ? i1 : i2);
            v = *(const float4*)(base + (size_t)m * 96 + ch * 32 + (k0 & 31));
        }
        *(float4*)(&As[row * 100 + k0]) = v;
    }
    __syncthreads();

    int lane = tid & 63, wid = tid >> 6;
    int waveM = wid & 1, waveN = wid >> 1;
    int l15 = lane & 15, quad = lane >> 4;
    floatx4 acc[2][2];
#pragma unroll
    for (int i = 0; i < 2; i++)
#pragma unroll
        for (int j = 0; j < 2; j++) acc[i][j] = (floatx4){0.f, 0.f, 0.f, 0.f};

#pragma unroll
    for (int kt = 0; kt < 96; kt += 32) {
        short8 ah[2], al[2];
#pragma unroll
        for (int mt = 0; mt < 2; mt++) {
            int r = waveM * 32 + mt * 16 + l15;
            split8(&As[r * 100 + kt + quad * 8], ah[mt], al[mt]);
        }
#pragma unroll
        for (int nt = 0; nt < 2; nt++) {
            int c = waveN * 32 + nt * 16 + l15;
            short8 bh, bl;
            split8(&Bs[c * 100 + kt + quad * 8], bh, bl);
#pragma unroll
            for (int mt = 0; mt < 2; mt++) {
                acc[mt][nt] = __builtin_amdgcn_mfma_f32_16x16x32_bf16(ah[mt], bh, acc[mt][nt], 0, 0, 0);
                acc[mt][nt] = __builtin_amdgcn_mfma_f32_16x16x32_bf16(ah[mt], bl, acc[mt][nt], 0, 0, 0);
                acc[mt][nt] = __builtin_amdgcn_mfma_f32_16x16x32_bf16(al[mt], bh, acc[mt][nt], 0, 0, 0);
            }
        }
    }

    float cb0[2], cwo[2];
#pragma unroll
    for (int nt = 0; nt < 2; nt++) {
        int col = waveN * 32 + nt * 16 + l15;
        cb0[nt] = sb0[col]; cwo[nt] = sWo[col];
    }
    float p[2][4];
#pragma unroll
    for (int mt = 0; mt < 2; mt++)
#pragma unroll
        for (int r = 0; r < 4; r++) {
            float s = 0.f;
#pragma unroll
            for (int nt = 0; nt < 2; nt++) {
                float h = acc[mt][nt][r] + cb0[nt];
                h = h > 0.f ? h : (expf(h) - 1.0f);
                s += h * cwo[nt];
            }
            p[mt][r] = s;
        }
#pragma unroll
    for (int mt = 0; mt < 2; mt++)
#pragma unroll
        for (int r = 0; r < 4; r++) {
#pragma unroll
            for (int msk = 1; msk < 16; msk <<= 1)
                p[mt][r] += __shfl_xor(p[mt][r], msk, 64);
        }
    if (l15 == 0) {
#pragma unroll
        for (int mt = 0; mt < 2; mt++)
#pragma unroll
            for (int r = 0; r < 4; r++) {
                int row = waveM * 32 + mt * 16 + quad * 4 + r;
                red[row][waveN] = p[mt][r];
            }
    }
    __syncthreads();
    if (tid < 64) {
        int m = m0 + tid;
        if (m < N) out[(size_t)m * 3 + ch] = red[tid][0] + red[tid][1] + bout[ch];
    }
}

// ================= host launch =================

extern "C" void kernel_launch(void* const* d_in, const int* in_sizes, int n_in,
                              void* d_out, int out_size, void* d_ws, size_t ws_size,
                              hipStream_t stream) {
    const float* x0 = (const float*)d_in[0];
    const float* x1 = (const float*)d_in[1];
    const float* x2 = (const float*)d_in[2];
    const int* ei0 = (const int*)d_in[3];
    const int* ei1 = (const int*)d_in[4];
    const int* ei2 = (const int*)d_in[5];
    const int* A1r = (const int*)d_in[6];
    const int* A1c = (const int*)d_in[7];
    const float* A1v = (const float*)d_in[8];
    const int* A2r = (const int*)d_in[9];
    const int* A2c = (const int*)d_in[10];
    const float* A2v = (const float*)d_in[11];
    const float* c1Wrel = (const float*)d_in[12];
    const float* c1brel = (const float*)d_in[13];
    const float* c1Wroot = (const float*)d_in[14];
    const float* c2Wrel = (const float*)d_in[15];
    const float* c2brel = (const float*)d_in[16];
    const float* c2Wroot = (const float*)d_in[17];
    const float* linW = (const float*)d_in[18];
    const float* linb = (const float*)d_in[19];
    const float* dW0 = (const float*)d_in[20];
    const float* db0 = (const float*)d_in[21];
    const float* dWout = (const float*)d_in[22];
    const float* dbout = (const float*)d_in[23];
    float* out = (float*)d_out;

    // ---- workspace (float words) ----
    float* ws = (float*)d_ws;
    unsigned short* h1hi = (unsigned short*)(ws + 400000);   // node-major, 8.4M ushorts [0.4M, 4.6M)
    unsigned short* h1lo = (unsigned short*)(ws + 4600000);  // node-major, 8.4M ushorts [4.6M, 8.8M)
    unsigned short* aggh = (unsigned short*)(ws + 8800000);  // bf16 agg, 8.4M ushorts [8.8M, 13.0M)
    float* ecat = ws + 17200000;                 // 6.3M words [17.2M, 23.5M)
    // binned intermediates overlay agg region (dead before gatherH writes aggh)
    int* bpacked = (int*)(ws + 13000000);        // 1,450,000 [13.0M, 14.45M)
    float* bval = ws + 13000000 + 1450000;       // 1,450,000 [14.45M, 15.9M) — disjoint from aggh
    // i1 overlays aggh+bpacked region (both dead after conv2lin): [8.8M, 13.6M) < 17.2M ✓
    float* i1 = ws + 8800000;
    // i2 overlays h1 planes (dead after conv2lin): [0.4M, 5.2M) ✓
    float* i2 = ws + 400000;
    int* hist_g = (int*)(ws + 23500000);         // NBUCK*NBLK = 115,020
    int* btot = (int*)(ws + 23615020);           // 325
    int* bbase = (int*)(ws + 23615344);          // 325
    int* offs = (int*)(ws + 23665632);           // 165,626
    int* csrc = (int*)(ws + 23831264);           // 1,450,000
    float* cval = ws + 25281392;                 // 400,000
    unsigned short* c2hi = (unsigned short*)(ws + 25681392); // 98,304 ushort
    unsigned short* c2lo = c2hi + 98304;
    unsigned short* lnhi = c2lo + 98304;                     // 36,864 ushort
    unsigned short* lnlo = lnhi + 36864;
    float* decWt = ws + 25681392 + 135168;       // 18,432 floats; ends ~25,834,992 (~103.3 MB)

    conv_weights<<<(153600 + 255) / 256, 256, 0, stream>>>(
        c2Wrel, c2Wroot, linW, dW0, c2hi, c2lo, lnhi, lnlo, decWt, btot);

    // ---- binned CSR build ----
    bin_hist<<<NBLK, 256, 0, stream>>>(ei0, ei1, ei2, A1r, A2r, hist_g, btot);
    hist_scan<<<NBUCK, 64, 0, stream>>>(hist_g, btot, bbase);
    bin_scatter<<<NBLK, 256, 0, stream>>>(ei0, ei1, ei2, A1r, A1c, A1v,
                                          A2r, A2c, A2v, hist_g, bpacked, bval);
    bucket_fill<<<NBUCK, 256, 0, stream>>>(bpacked, bval, bbase, offs, csrc, cval);

    // ---- encoder ----
    conv1_b<<<1027, 256, 0, stream>>>(offs, csrc, x0, x1, x2,
                                      c1Wrel, c1Wroot, c1brel, h1hi, h1lo);
    gatherH_b<<<((size_t)NT * 16 + 255) / 256, 256, 0, stream>>>(h1hi, offs, csrc, aggh);
    conv2lin<<<1027, 256, 0, stream>>>(aggh, h1hi, h1lo, c2hi, c2lo, c2brel,
                                       lnhi, lnlo, linb, ecat);

    // ---- interpolation (i1 over aggh/bpacked, i2 over h1 planes — all dead) ----
    interp_b<<<((size_t)2 * N0 * 24 + 255) / 256, 256, 0, stream>>>(
        ecat, offs, csrc, cval, i1, i2);

    // ---- decoder ----
    dim3 gd(782, 3);
    decoder_mfma<<<gd, 256, 0, stream>>>(ecat, i1, i2, decWt, db0, dWout, dbout, out, N0);
}

// Round 16
// 289.727 us; speedup vs baseline: 1.2615x; 1.0299x over previous
//
#include <hip/hip_runtime.h>
#include <math.h>

#define N0 50000
#define N1 12500
#define N2 3125
#define NNZ 200000
#define NE0 800000
#define NE1 200000
#define NE2 50000
#define NT 65625           // N0+N1+N2
#define SEG_TOT 165625     // NT + 2*N0
#define EDGE_TOT 1050000   // NE0+NE1+NE2
#define ITEM_TOT 1450000   // EDGE_TOT + 2*NNZ
#define NBUCK 324          // ceil(SEG_TOT/512)
#define SPB 512            // segs per bucket
#define NBLK 355           // ceil(ITEM_TOT/4096)

typedef __attribute__((ext_vector_type(8))) short short8;
typedef __attribute__((ext_vector_type(8))) unsigned short ushort8;
typedef __attribute__((ext_vector_type(4))) unsigned short ushort4v;
typedef __attribute__((ext_vector_type(4))) float floatx4;

__device__ inline void split_bf16(float x, unsigned short& hi, unsigned short& lo) {
    unsigned xb = __float_as_uint(x);
    hi = (unsigned short)(xb >> 16);
    float hf = __uint_as_float((unsigned)hi << 16);
    lo = (unsigned short)(__float_as_uint(x - hf) >> 16);
}

__device__ inline unsigned short bf16_rne(float x) {
    unsigned xb = __float_as_uint(x);
    return (unsigned short)((xb + 0x7fff + ((xb >> 16) & 1)) >> 16);
}

// split 8 contiguous fp32 (LDS) into hi/lo bf16 frags
__device__ inline void split8(const float* p, short8& hi, short8& lo) {
    float4 u0 = *(const float4*)p;
    float4 u1 = *(const float4*)(p + 4);
    float f[8] = {u0.x, u0.y, u0.z, u0.w, u1.x, u1.y, u1.z, u1.w};
#pragma unroll
    for (int j = 0; j < 8; j++) {
        unsigned short h, l;
        split_bf16(f[j], h, l);
        hi[j] = (short)h; lo[j] = (short)l;
    }
}

// ================= binned CSR build =================
// seg space: [0,50000) L0 nodes, [50000,62500) L1, [62500,65625) L2,
// [65625,115625) interp1 rows, [115625,165625) interp2 rows.

__device__ inline int item_seg(int t, const int* __restrict__ ei0,
                               const int* __restrict__ ei1, const int* __restrict__ ei2,
                               const int* __restrict__ A1r, const int* __restrict__ A2r) {
    if (t < NE0) return ei0[NE0 + t];
    if (t < NE0 + NE1) return 50000 + ei1[NE1 + (t - NE0)];
    if (t < EDGE_TOT) return 62500 + ei2[NE2 + (t - (NE0 + NE1))];
    if (t < EDGE_TOT + NNZ) return NT + A1r[t - EDGE_TOT];
    return NT + N0 + A2r[t - (EDGE_TOT + NNZ)];
}

// A: per-block bucket histogram -> hist_g[bucket*NBLK + blk]; also bucket totals
__global__ __launch_bounds__(256) void bin_hist(const int* __restrict__ ei0,
        const int* __restrict__ ei1, const int* __restrict__ ei2,
        const int* __restrict__ A1r, const int* __restrict__ A2r,
        int* __restrict__ hist_g, int* __restrict__ btot) {
    __shared__ int h[NBUCK];
    for (int i = threadIdx.x; i < NBUCK; i += 256) h[i] = 0;
    __syncthreads();
    int base = blockIdx.x * 4096;
#pragma unroll
    for (int q = 0; q < 16; q++) {
        int t = base + q * 256 + threadIdx.x;
        if (t < ITEM_TOT) atomicAdd(&h[item_seg(t, ei0, ei1, ei2, A1r, A2r) >> 9], 1);
    }
    __syncthreads();
    for (int i = threadIdx.x; i < NBUCK; i += 256) {
        int v = h[i];
        hist_g[i * NBLK + blockIdx.x] = v;
        if (v) atomicAdd(&btot[i], v);
    }
}

// B3: per-bucket exclusive scan of hist_g row + bucket_base
__global__ void hist_scan(int* __restrict__ hist_g, const int* __restrict__ btot,
                          int* __restrict__ bbase) {
    int b = blockIdx.x, lane = threadIdx.x;
    int s = 0;
    for (int j = lane; j < b; j += 64) s += btot[j];
#pragma unroll
    for (int o = 32; o > 0; o >>= 1) s += __shfl_down(s, o, 64);
    int base = __shfl(s, 0, 64);
    if (lane == 0) {
        bbase[b] = base;
        if (b == NBUCK - 1) bbase[NBUCK] = ITEM_TOT;
    }
    int v[6], ts = 0;
#pragma unroll
    for (int q = 0; q < 6; q++) {
        int i = lane * 6 + q;
        v[q] = (i < NBLK) ? hist_g[b * NBLK + i] : 0;
        ts += v[q];
    }
    int sc = ts;
#pragma unroll
    for (int o = 1; o < 64; o <<= 1) {
        int t2 = __shfl_up(sc, o, 64);
        if (lane >= o) sc += t2;
    }
    int run = base + sc - ts;
#pragma unroll
    for (int q = 0; q < 6; q++) {
        int i = lane * 6 + q;
        if (i < NBLK) hist_g[b * NBLK + i] = run;
        run += v[q];
    }
}

// C: scatter items into bucket-ordered packed array
__global__ __launch_bounds__(256) void bin_scatter(const int* __restrict__ ei0,
        const int* __restrict__ ei1, const int* __restrict__ ei2,
        const int* __restrict__ A1r, const int* __restrict__ A1c, const float* __restrict__ A1v,
        const int* __restrict__ A2r, const int* __restrict__ A2c, const float* __restrict__ A2v,
        const int* __restrict__ hist_g, int* __restrict__ bpacked, float* __restrict__ bval) {
    __shared__ int cur[NBUCK];
    for (int i = threadIdx.x; i < NBUCK; i += 256) cur[i] = hist_g[i * NBLK + blockIdx.x];
    __syncthreads();
    int base = blockIdx.x * 4096;
#pragma unroll
    for (int q = 0; q < 16; q++) {
        int t = base + q * 256 + threadIdx.x;
        if (t >= ITEM_TOT) continue;
        int seg, pay;
        float val = 0.f;
        bool isv = false;
        if (t < NE0) { seg = ei0[NE0 + t]; pay = ei0[t]; }
        else if (t < NE0 + NE1) { int e = t - NE0; seg = 50000 + ei1[NE1 + e]; pay = ei1[e]; }
        else if (t < EDGE_TOT) { int e = t - (NE0 + NE1); seg = 62500 + ei2[NE2 + e]; pay = ei2[e]; }
        else if (t < EDGE_TOT + NNZ) { int k = t - EDGE_TOT; seg = NT + A1r[k]; pay = A1c[k]; val = A1v[k]; isv = true; }
        else { int k = t - (EDGE_TOT + NNZ); seg = NT + N0 + A2r[k]; pay = A2c[k]; val = A2v[k]; isv = true; }
        int bk = seg >> 9;
        int p = atomicAdd(&cur[bk], 1);
        bpacked[p] = ((seg - (bk << 9)) << 16) | pay;  // seg_local<512, pay<65536
        if (isv) bval[p] = val;
    }
}

// E: per-bucket count + scan + fill; writes offs[seg]=start directly.
__global__ __launch_bounds__(256) void bucket_fill(const int* __restrict__ bpacked,
        const float* __restrict__ bval, const int* __restrict__ bbase,
        int* __restrict__ offs, int* __restrict__ csrc, float* __restrict__ cval) {
    __shared__ int cnt[SPB];
    __shared__ int wsum2[4];
    int b = blockIdx.x, tid = threadIdx.x;
    int segbase = b * SPB;
    int seglim = SEG_TOT - segbase;
    if (seglim > SPB) seglim = SPB;
    int ibeg = bbase[b], iend = bbase[b + 1];
    for (int i = tid; i < SPB; i += 256) cnt[i] = 0;
    __syncthreads();
    for (int i = ibeg + tid; i < iend; i += 256)
        atomicAdd(&cnt[bpacked[i] >> 16], 1);
    __syncthreads();
    int lane = tid & 63, wid = tid >> 6;
    int v0 = cnt[tid * 2], v1 = cnt[tid * 2 + 1];
    int ts = v0 + v1, sc = ts;
#pragma unroll
    for (int o = 1; o < 64; o <<= 1) {
        int t2 = __shfl_up(sc, o, 64);
        if (lane >= o) sc += t2;
    }
    if (lane == 63) wsum2[wid] = sc;
    __syncthreads();
    int woff = 0;
    for (int w = 0; w < wid; w++) woff += wsum2[w];
    int ex = ibeg + woff + sc - ts;  // start position of seg tid*2
    __syncthreads();
    cnt[tid * 2] = ex;
    cnt[tid * 2 + 1] = ex + v0;
    if (tid * 2 < seglim) offs[segbase + tid * 2] = ex;
    if (tid * 2 + 1 < seglim) offs[segbase + tid * 2 + 1] = ex + v0;
    if (b == NBUCK - 1 && tid == 0) offs[SEG_TOT] = ITEM_TOT;
    __syncthreads();
    for (int i = ibeg + tid; i < iend; i += 256) {
        int w2 = bpacked[i];
        int sl = w2 >> 16, pay = w2 & 0xffff;
        int p = atomicAdd(&cnt[sl], 1);
        csrc[p] = pay;
        if (segbase + sl >= NT) cval[p - EDGE_TOT] = bval[i];
    }
}

// ================= batched gathers =================
// segment n spans [offs[n], offs[n+1])

__device__ inline void acc_u4(uint4 u, float* a) {
    a[0] += __uint_as_float(u.x << 16);
    a[1] += __uint_as_float(u.x & 0xffff0000u);
    a[2] += __uint_as_float(u.y << 16);
    a[3] += __uint_as_float(u.y & 0xffff0000u);
    a[4] += __uint_as_float(u.z << 16);
    a[5] += __uint_as_float(u.z & 0xffff0000u);
    a[6] += __uint_as_float(u.w << 16);
    a[7] += __uint_as_float(u.w & 0xffff0000u);
}

// node-major bf16 hi plane; 16 lanes/node x uint4 (8 feats), edge loop unrolled x4.
// Output agg is bf16-RNE (hi only).
__global__ __launch_bounds__(256) void gatherH_b(const unsigned short* __restrict__ h1hi,
                                                 const int* __restrict__ offs,
                                                 const int* __restrict__ csrc,
                                                 unsigned short* __restrict__ aggh) {
    int t = blockIdx.x * blockDim.x + threadIdx.x;
    int n = t >> 4, g = t & 15;
    if (n >= NT) return;
    int nb = (n < 50000) ? 0 : (n < 62500 ? 50000 : 62500);
    float a[8] = {};
    int b = offs[n], e = offs[n + 1];
    int j = b;
    for (; j + 3 < e; j += 4) {
        int s0 = csrc[j], s1 = csrc[j + 1], s2 = csrc[j + 2], s3 = csrc[j + 3];
        uint4 u0 = *(const uint4*)(h1hi + (size_t)(nb + s0) * 128 + g * 8);
        uint4 u1 = *(const uint4*)(h1hi + (size_t)(nb + s1) * 128 + g * 8);
        uint4 u2 = *(const uint4*)(h1hi + (size_t)(nb + s2) * 128 + g * 8);
        uint4 u3 = *(const uint4*)(h1hi + (size_t)(nb + s3) * 128 + g * 8);
        acc_u4(u0, a);
        acc_u4(u1, a);
        acc_u4(u2, a);
        acc_u4(u3, a);
    }
    for (; j < e; j++) {
        uint4 u0 = *(const uint4*)(h1hi + (size_t)(nb + csrc[j]) * 128 + g * 8);
        acc_u4(u0, a);
    }
    ushort8 o;
#pragma unroll
    for (int q = 0; q < 8; q++) o[q] = bf16_rne(a[q]);
    *(ushort8*)(aggh + (size_t)n * 128 + g * 8) = o;
}

// interp (all bf16): reads bf16 ecat, writes bf16 i1/i2. 24 threads/node (4 feats each).
__global__ __launch_bounds__(256) void interp_b(const unsigned short* __restrict__ ecat16,
                                                const int* __restrict__ offs,
                                                const int* __restrict__ csrc,
                                                const float* __restrict__ cval,
                                                unsigned short* __restrict__ i1,
                                                unsigned short* __restrict__ i2) {
    int t = blockIdx.x * blockDim.x + threadIdx.x;
    int ng = t / 24, g = t % 24;
    if (ng >= 2 * N0) return;
    int a = (ng >= N0) ? 1 : 0;
    int nl = ng - a * N0;
    const unsigned short* e = ecat16 + (size_t)(a ? 62500 : 50000) * 96;
    unsigned short* ob = a ? i2 : i1;
    int seg = NT + ng;
    float sx = 0, sy = 0, sz = 0, sw = 0;
    int b = offs[seg], en = offs[seg + 1];
    int j = b;
    for (; j + 1 < en; j += 2) {
        int c0 = csrc[j], c1 = csrc[j + 1];
        float v0 = cval[j - EDGE_TOT], v1 = cval[j + 1 - EDGE_TOT];
        uint2 u0 = *(const uint2*)(e + (size_t)c0 * 96 + g * 4);
        uint2 u1 = *(const uint2*)(e + (size_t)c1 * 96 + g * 4);
        sx += v0 * __uint_as_float(u0.x << 16) + v1 * __uint_as_float(u1.x << 16);
        sy += v0 * __uint_as_float(u0.x & 0xffff0000u) + v1 * __uint_as_float(u1.x & 0xffff0000u);
        sz += v0 * __uint_as_float(u0.y << 16) + v1 * __uint_as_float(u1.y << 16);
        sw += v0 * __uint_as_float(u0.y & 0xffff0000u) + v1 * __uint_as_float(u1.y & 0xffff0000u);
    }
    if (j < en) {
        int c0 = csrc[j];
        float v0 = cval[j - EDGE_TOT];
        uint2 u0 = *(const uint2*)(e + (size_t)c0 * 96 + g * 4);
        sx += v0 * __uint_as_float(u0.x << 16);
        sy += v0 * __uint_as_float(u0.x & 0xffff0000u);
        sz += v0 * __uint_as_float(u0.y << 16);
        sw += v0 * __uint_as_float(u0.y & 0xffff0000u);
    }
    uint2 o = {(unsigned)bf16_rne(sx) | ((unsigned)bf16_rne(sy) << 16),
               (unsigned)bf16_rne(sz) | ((unsigned)bf16_rne(sw) << 16)};
    *(uint2*)(ob + (size_t)nl * 96 + g * 4) = o;
}

// ================= weight preconvert (also zeroes btot) =================
__global__ void conv_weights(const float* __restrict__ c2Wrel, const float* __restrict__ c2Wroot,
                             const float* __restrict__ linW, const float* __restrict__ dW0,
                             unsigned short* __restrict__ c2hi, unsigned short* __restrict__ c2lo,
                             unsigned short* __restrict__ lhi, unsigned short* __restrict__ llo,
                             float* __restrict__ decWt, int* __restrict__ btot) {
    int t = blockIdx.x * blockDim.x + threadIdx.x;
    if (t <= NBUCK) btot[t] = 0;
    if (t < 98304) {
        int i = t / 32768, r = t % 32768;
        int n = r / 256, k = r % 256;
        float w = (k < 128) ? c2Wrel[i * 16384 + k * 128 + n]
                            : c2Wroot[i * 16384 + (k - 128) * 128 + n];
        unsigned short hi, lo;
        split_bf16(w, hi, lo);
        c2hi[t] = hi; c2lo[t] = lo;
    } else if (t < 135168) {
        int u = t - 98304;
        int i = u / 12288, r = u % 12288;
        int n = r / 128, k = r % 128;
        unsigned short hi, lo;
        split_bf16(linW[i * 12288 + k * 96 + n], hi, lo);
        lhi[u] = hi; llo[u] = lo;
    } else if (t < 153600) {
        int u = t - 135168;
        int chn = u / 6144, r = u % 6144;
        int col = r / 96, k = r % 96;
        decWt[u] = dW0[chn * 6144 + k * 64 + col];
    }
}

// ===== conv1 (fp32, K=12, 64x128 single-pass) with fused CSR gather =====
__global__ __launch_bounds__(256) void conv1_b(
        const int* __restrict__ offs, const int* __restrict__ csrc,
        const float* __restrict__ x0, const float* __restrict__ x1,
        const float* __restrict__ x2,
        const float* __restrict__ Wrel, const float* __restrict__ Wroot,
        const float* __restrict__ brel,
        unsigned short* __restrict__ h1hi, unsigned short* __restrict__ h1lo) {
    __shared__ float As[12][65];
    __shared__ float Ws[12][128];
    int bx = blockIdx.x;
    int l, lbk;
    if (bx < 782) { l = 0; lbk = bx; }
    else if (bx < 978) { l = 1; lbk = bx - 782; }
    else { l = 2; lbk = bx - 978; }
    int nb = (l == 0) ? 0 : (l == 1 ? 50000 : 62500);
    int M = (l == 0) ? N0 : (l == 1 ? N1 : N2);
    const float* xl = (l == 0) ? x0 : (l == 1 ? x1 : x2);
    const float* W1 = Wrel + l * 768;
    const float* W2 = Wroot + l * 768;
    const float* bias = brel + l * 128;
    int m0 = lbk * 64;
    int tid = threadIdx.x;

    {
        int row = tid >> 2, sub = tid & 3;
        int m = m0 + row;
        float a6[6] = {};
        if (m < M) {
            int jb = offs[nb + m], je = offs[nb + m + 1];
            for (int j = jb + sub; j < je; j += 4) {
                const float* p = xl + (size_t)csrc[j] * 6;
                a6[0] += p[0]; a6[1] += p[1]; a6[2] += p[2];
                a6[3] += p[3]; a6[4] += p[4]; a6[5] += p[5];
            }
        }
#pragma unroll
        for (int msk = 1; msk < 4; msk <<= 1) {
#pragma unroll
            for (int q = 0; q < 6; q++) a6[q] += __shfl_xor(a6[q], msk, 64);
        }
        if (sub == 0) {
#pragma unroll
            for (int q = 0; q < 6; q++) As[q][row] = (m < M) ? a6[q] : 0.f;
        } else if (sub == 1) {
#pragma unroll
            for (int q = 0; q < 6; q++)
                As[6 + q][row] = (m < M) ? xl[(size_t)m * 6 + q] : 0.f;
        }
    }
    for (int idx = tid; idx < 1536; idx += 256) {
        int kk = idx >> 7, nn2 = idx & 127;
        Ws[kk][nn2] = (kk < 6) ? W1[kk * 128 + nn2] : W2[(kk - 6) * 128 + nn2];
    }
    __syncthreads();

    int tm = tid >> 4, tn = tid & 15;
    float acc[4][8] = {};
#pragma unroll
    for (int k = 0; k < 12; k++) {
        float av[4], wv[8];
#pragma unroll
        for (int i = 0; i < 4; i++) av[i] = As[k][tm * 4 + i];
#pragma unroll
        for (int j = 0; j < 4; j++) { wv[j] = Ws[k][tn * 4 + j]; wv[4 + j] = Ws[k][64 + tn * 4 + j]; }
#pragma unroll
        for (int i = 0; i < 4; i++)
#pragma unroll
            for (int j = 0; j < 8; j++) acc[i][j] += av[i] * wv[j];
    }
#pragma unroll
    for (int i = 0; i < 4; i++) {
        int m = m0 + tm * 4 + i;
        if (m >= M) continue;
#pragma unroll
        for (int half = 0; half < 2; half++) {
            int c0 = half * 64 + tn * 4;
            unsigned short hs[4], ls[4];
#pragma unroll
            for (int j = 0; j < 4; j++) {
                float v = fmaxf(acc[i][half * 4 + j] + bias[c0 + j], 0.f);
                split_bf16(v, hs[j], ls[j]);
            }
            uint2 ph = {(unsigned)hs[0] | ((unsigned)hs[1] << 16),
                        (unsigned)hs[2] | ((unsigned)hs[3] << 16)};
            uint2 pl = {(unsigned)ls[0] | ((unsigned)ls[1] << 16),
                        (unsigned)ls[2] | ((unsigned)ls[3] << 16)};
            size_t off = (size_t)(nb + m) * 128 + c0;
            *(uint2*)(h1hi + off) = ph;
            *(uint2*)(h1lo + off) = pl;
        }
    }
}

// ================= fused conv2+lin (split-bf16 MFMA) =================
// A-tile: kt<128 -> bf16 agg (hi only); kt>=128 -> pre-split h1 planes.
// Output ecat is bf16-RNE.
__global__ __launch_bounds__(256) void conv2lin(
        const unsigned short* __restrict__ aggh,
        const unsigned short* __restrict__ h1hi, const unsigned short* __restrict__ h1lo,
        const unsigned short* __restrict__ c2hi, const unsigned short* __restrict__ c2lo,
        const float* __restrict__ c2b,
        const unsigned short* __restrict__ lnhi, const unsigned short* __restrict__ lnlo,
        const float* __restrict__ lnb, unsigned short* __restrict__ ecat16) {
    __shared__ unsigned short smem[25088];  // 50.2 KB union
    unsigned short* Ah = smem;              // 64*40
    unsigned short* Al = smem + 2560;
    unsigned short* Bh = smem + 5120;       // 128*40
    unsigned short* Bl = smem + 10240;
    unsigned short* Hh = smem;              // 64*136 (phase 2)
    unsigned short* Hl = smem + 8704;
    unsigned short* B2h = smem + 17408;     // 96*40
    unsigned short* B2l = smem + 21248;
    const int LDA = 40;

    int bx = blockIdx.x;
    int l, lbk;
    if (bx < 782) { l = 0; lbk = bx; }
    else if (bx < 978) { l = 1; lbk = bx - 782; }
    else { l = 2; lbk = bx - 978; }
    int nb = (l == 0) ? 0 : (l == 1 ? 50000 : 62500);
    int M = (l == 0) ? N0 : (l == 1 ? N1 : N2);
    const unsigned short* A1h = aggh + (size_t)nb * 128;
    const unsigned short* A2h = h1hi + (size_t)nb * 128;
    const unsigned short* A2l = h1lo + (size_t)nb * 128;
    const unsigned short* W1h = c2hi + l * 32768;
    const unsigned short* W1l = c2lo + l * 32768;
    const float* b1 = c2b + l * 128;
    const unsigned short* W2h = lnhi + l * 12288;
    const unsigned short* W2l = lnlo + l * 12288;
    const float* b2 = lnb + l * 96;
    unsigned short* C = ecat16 + (size_t)nb * 96;
    int m0 = lbk * 64;

    int tid = threadIdx.x;
    int lane = tid & 63, wid = tid >> 6;
    int waveM = wid & 1, waveN = wid >> 1;
    int l15 = lane & 15, quad = lane >> 4;
    int arow = tid >> 2, acol = (tid & 3) * 8;
    int brow = tid >> 1, bcol = (tid & 1) * 16;

    floatx4 acc[2][4];
#pragma unroll
    for (int i = 0; i < 2; i++)
#pragma unroll
        for (int j = 0; j < 4; j++) acc[i][j] = (floatx4){0.f, 0.f, 0.f, 0.f};

    // ---- phase 1: K=256 ----
    for (int kt = 0; kt < 256; kt += 32) {
        bool hasLo = (kt >= 128);
        __syncthreads();
        {
            int m = m0 + arow;
            ushort8 hv = (ushort8)0, lv = (ushort8)0;
            if (m < M) {
                int kg = kt + acol;
                if (!hasLo) {
                    hv = *(const ushort8*)(A1h + (size_t)m * 128 + kg);
                } else {
                    size_t off = (size_t)m * 128 + (kg - 128);
                    hv = *(const ushort8*)(A2h + off);
                    lv = *(const ushort8*)(A2l + off);
                }
            }
            *(ushort8*)(&Ah[arow * LDA + acol]) = hv;
            if (hasLo) *(ushort8*)(&Al[arow * LDA + acol]) = lv;
        }
        {
            const unsigned short* ph = W1h + (size_t)brow * 256 + kt + bcol;
            const unsigned short* pl = W1l + (size_t)brow * 256 + kt + bcol;
            *(ushort8*)(&Bh[brow * LDA + bcol]) = *(const ushort8*)ph;
            *(ushort8*)(&Bh[brow * LDA + bcol + 8]) = *(const ushort8*)(ph + 8);
            *(ushort8*)(&Bl[brow * LDA + bcol]) = *(const ushort8*)pl;
            *(ushort8*)(&Bl[brow * LDA + bcol + 8]) = *(const ushort8*)(pl + 8);
        }
        __syncthreads();
        short8 af[2][2];
#pragma unroll
        for (int mt = 0; mt < 2; mt++) {
            int r = waveM * 32 + mt * 16 + l15;
            af[mt][0] = *(const short8*)(&Ah[r * LDA + quad * 8]);
            if (hasLo) af[mt][1] = *(const short8*)(&Al[r * LDA + quad * 8]);
        }
#pragma unroll
        for (int nt = 0; nt < 4; nt++) {
            int c = waveN * 64 + nt * 16 + l15;
            short8 bh = *(const short8*)(&Bh[c * LDA + quad * 8]);
            short8 bl = *(const short8*)(&Bl[c * LDA + quad * 8]);
#pragma unroll
            for (int mt = 0; mt < 2; mt++) {
                acc[mt][nt] = __builtin_amdgcn_mfma_f32_16x16x32_bf16(af[mt][0], bh, acc[mt][nt], 0, 0, 0);
                acc[mt][nt] = __builtin_amdgcn_mfma_f32_16x16x32_bf16(af[mt][0], bl, acc[mt][nt], 0, 0, 0);
                if (hasLo)
                    acc[mt][nt] = __builtin_amdgcn_mfma_f32_16x16x32_bf16(af[mt][1], bh, acc[mt][nt], 0, 0, 0);
            }
        }
    }

    // ---- transition: h2 tile -> LDS hi/lo ----
    __syncthreads();
    {
        float bs1[4];
#pragma unroll
        for (int nt = 0; nt < 4; nt++) bs1[nt] = b1[waveN * 64 + nt * 16 + l15];
#pragma unroll
        for (int mt = 0; mt < 2; mt++)
#pragma unroll
            for (int nt = 0; nt < 4; nt++)
#pragma unroll
                for (int r = 0; r < 4; r++) {
                    int row = waveM * 32 + mt * 16 + quad * 4 + r;
                    int col = waveN * 64 + nt * 16 + l15;
                    float v = fmaxf(acc[mt][nt][r] + bs1[nt], 0.f);
                    unsigned short h, lo2;
                    split_bf16(v, h, lo2);
                    Hh[row * 136 + col] = h;
                    Hl[row * 136 + col] = lo2;
                }
    }

    // ---- phase 2: K=128, J=96 ----
    floatx4 acc2[2][3];
#pragma unroll
    for (int i = 0; i < 2; i++)
#pragma unroll
        for (int j = 0; j < 3; j++) acc2[i][j] = (floatx4){0.f, 0.f, 0.f, 0.f};

    for (int kt = 0; kt < 128; kt += 32) {
        __syncthreads();
        if (brow < 96) {
            const unsigned short* ph = W2h + (size_t)brow * 128 + kt + bcol;
            const unsigned short* pl = W2l + (size_t)brow * 128 + kt + bcol;
            *(ushort8*)(&B2h[brow * LDA + bcol]) = *(const ushort8*)ph;
            *(ushort8*)(&B2h[brow * LDA + bcol + 8]) = *(const ushort8*)(ph + 8);
            *(ushort8*)(&B2l[brow * LDA + bcol]) = *(const ushort8*)pl;
            *(ushort8*)(&B2l[brow * LDA + bcol + 8]) = *(const ushort8*)(pl + 8);
        }
        __syncthreads();
        short8 af2[2][2];
#pragma unroll
        for (int mt = 0; mt < 2; mt++) {
            int r = waveM * 32 + mt * 16 + l15;
            af2[mt][0] = *(const short8*)(&Hh[r * 136 + kt + quad * 8]);
            af2[mt][1] = *(const short8*)(&Hl[r * 136 + kt + quad * 8]);
        }
#pragma unroll
        for (int nt = 0; nt < 3; nt++) {
            int c = waveN * 48 + nt * 16 + l15;
            short8 bh = *(const short8*)(&B2h[c * LDA + quad * 8]);
            short8 bl = *(const short8*)(&B2l[c * LDA + quad * 8]);
#pragma unroll
            for (int mt = 0; mt < 2; mt++) {
                acc2[mt][nt] = __builtin_amdgcn_mfma_f32_16x16x32_bf16(af2[mt][0], bh, acc2[mt][nt], 0, 0, 0);
                acc2[mt][nt] = __builtin_amdgcn_mfma_f32_16x16x32_bf16(af2[mt][0], bl, acc2[mt][nt], 0, 0, 0);
                acc2[mt][nt] = __builtin_amdgcn_mfma_f32_16x16x32_bf16(af2[mt][1], bh, acc2[mt][nt], 0, 0, 0);
            }
        }
    }

    // ---- epilogue: bf16-RNE ecat ----
    float bs2[3];
#pragma unroll
    for (int nt = 0; nt < 3; nt++) bs2[nt] = b2[waveN * 48 + nt * 16 + l15];
#pragma unroll
    for (int mt = 0; mt < 2; mt++)
#pragma unroll
        for (int r = 0; r < 4; r++) {
            int grow = m0 + waveM * 32 + mt * 16 + quad * 4 + r;
            if (grow >= M) continue;
#pragma unroll
            for (int nt = 0; nt < 3; nt++) {
                int col = waveN * 48 + nt * 16 + l15;
                C[(size_t)grow * 96 + col] = bf16_rne(acc2[mt][nt][r] + bs2[nt]);
            }
        }
}

// ================= MFMA decoder (bf16 A-inputs, A-lo == 0) =================
__global__ __launch_bounds__(256) void decoder_mfma(
        const unsigned short* __restrict__ e0, const unsigned short* __restrict__ i1,
        const unsigned short* __restrict__ i2, const float* __restrict__ decWt,
        const float* __restrict__ b0, const float* __restrict__ Wout,
        const float* __restrict__ bout, float* __restrict__ out, int N) {
    __shared__ unsigned short As16[64 * 104];  // [row][k], pitch 104 ushorts (2-way alias: free)
    __shared__ float Bs[6400];                 // [col][k], pitch 100 fp32
    __shared__ float red[64][2];
    __shared__ float sb0[64], sWo[64];
    int ch = blockIdx.y;
    int tid = threadIdx.x;
    int m0 = blockIdx.x * 64;

    for (int idx = tid; idx < 1536; idx += 256) {
        int col = idx / 24, k0 = (idx % 24) * 4;
        *(float4*)(&Bs[col * 100 + k0]) = *(const float4*)(decWt + ch * 6144 + col * 96 + k0);
    }
    if (tid < 64) { sb0[tid] = b0[ch * 64 + tid]; sWo[tid] = Wout[ch * 64 + tid]; }
    for (int idx = tid; idx < 1536; idx += 256) {
        int row = idx / 24, k0 = (idx % 24) * 4;
        int m = m0 + row;
        uint2 v = {0u, 0u};
        if (m < N) {
            const unsigned short* base = (k0 < 32) ? e0 : (k0 < 64 ? i1 : i2);
            v = *(const uint2*)(base + (size_t)m * 96 + ch * 32 + (k0 & 31));
        }
        *(uint2*)(&As16[row * 104 + k0]) = v;
    }
    __syncthreads();

    int lane = tid & 63, wid = tid >> 6;
    int waveM = wid & 1, waveN = wid >> 1;
    int l15 = lane & 15, quad = lane >> 4;
    floatx4 acc[2][2];
#pragma unroll
    for (int i = 0; i < 2; i++)
#pragma unroll
        for (int j = 0; j < 2; j++) acc[i][j] = (floatx4){0.f, 0.f, 0.f, 0.f};

#pragma unroll
    for (int kt = 0; kt < 96; kt += 32) {
        short8 ah[2];
#pragma unroll
        for (int mt = 0; mt < 2; mt++) {
            int r = waveM * 32 + mt * 16 + l15;
            ah[mt] = *(const short8*)(&As16[r * 104 + kt + quad * 8]);
        }
#pragma unroll
        for (int nt = 0; nt < 2; nt++) {
            int c = waveN * 32 + nt * 16 + l15;
            short8 bh, bl;
            split8(&Bs[c * 100 + kt + quad * 8], bh, bl);
#pragma unroll
            for (int mt = 0; mt < 2; mt++) {
                acc[mt][nt] = __builtin_amdgcn_mfma_f32_16x16x32_bf16(ah[mt], bh, acc[mt][nt], 0, 0, 0);
                acc[mt][nt] = __builtin_amdgcn_mfma_f32_16x16x32_bf16(ah[mt], bl, acc[mt][nt], 0, 0, 0);
            }
        }
    }

    float cb0[2], cwo[2];
#pragma unroll
    for (int nt = 0; nt < 2; nt++) {
        int col = waveN * 32 + nt * 16 + l15;
        cb0[nt] = sb0[col]; cwo[nt] = sWo[col];
    }
    float p[2][4];
#pragma unroll
    for (int mt = 0; mt < 2; mt++)
#pragma unroll
        for (int r = 0; r < 4; r++) {
            float s = 0.f;
#pragma unroll
            for (int nt = 0; nt < 2; nt++) {
                float h = acc[mt][nt][r] + cb0[nt];
                h = h > 0.f ? h : (expf(h) - 1.0f);
                s += h * cwo[nt];
            }
            p[mt][r] = s;
        }
#pragma unroll
    for (int mt = 0; mt < 2; mt++)
#pragma unroll
        for (int r = 0; r < 4; r++) {
#pragma unroll
            for (int msk = 1; msk < 16; msk <<= 1)
                p[mt][r] += __shfl_xor(p[mt][r], msk, 64);
        }
    if (l15 == 0) {
#pragma unroll
        for (int mt = 0; mt < 2; mt++)
#pragma unroll
            for (int r = 0; r < 4; r++) {
                int row = waveM * 32 + mt * 16 + quad * 4 + r;
                red[row][waveN] = p[mt][r];
            }
    }
    __syncthreads();
    if (tid < 64) {
        int m = m0 + tid;
        if (m < N) out[(size_t)m * 3 + ch] = red[tid][0] + red[tid][1] + bout[ch];
    }
}

// ================= host launch =================

extern "C" void kernel_launch(void* const* d_in, const int* in_sizes, int n_in,
                              void* d_out, int out_size, void* d_ws, size_t ws_size,
                              hipStream_t stream) {
    const float* x0 = (const float*)d_in[0];
    const float* x1 = (const float*)d_in[1];
    const float* x2 = (const float*)d_in[2];
    const int* ei0 = (const int*)d_in[3];
    const int* ei1 = (const int*)d_in[4];
    const int* ei2 = (const int*)d_in[5];
    const int* A1r = (const int*)d_in[6];
    const int* A1c = (const int*)d_in[7];
    const float* A1v = (const float*)d_in[8];
    const int* A2r = (const int*)d_in[9];
    const int* A2c = (const int*)d_in[10];
    const float* A2v = (const float*)d_in[11];
    const float* c1Wrel = (const float*)d_in[12];
    const float* c1brel = (const float*)d_in[13];
    const float* c1Wroot = (const float*)d_in[14];
    const float* c2Wrel = (const float*)d_in[15];
    const float* c2brel = (const float*)d_in[16];
    const float* c2Wroot = (const float*)d_in[17];
    const float* linW = (const float*)d_in[18];
    const float* linb = (const float*)d_in[19];
    const float* dW0 = (const float*)d_in[20];
    const float* db0 = (const float*)d_in[21];
    const float* dWout = (const float*)d_in[22];
    const float* dbout = (const float*)d_in[23];
    float* out = (float*)d_out;

    // ---- workspace (float words) ----
    float* ws = (float*)d_ws;
    unsigned short* h1hi = (unsigned short*)(ws + 400000);   // [0.4M, 4.6M)
    unsigned short* h1lo = (unsigned short*)(ws + 4600000);  // [4.6M, 8.8M)
    unsigned short* aggh = (unsigned short*)(ws + 8800000);  // [8.8M, 13.0M)
    unsigned short* ecat16 = (unsigned short*)(ws + 17200000); // 6.3M ushorts [17.2M, 20.35M)
    int* bpacked = (int*)(ws + 13000000);        // [13.0M, 14.45M)
    float* bval = ws + 13000000 + 1450000;       // [14.45M, 15.9M)
    // i1 (bf16, 4.8M ushorts = 2.4M words) overlays aggh (dead after conv2lin): [8.8M, 11.2M) ✓
    unsigned short* i1 = (unsigned short*)(ws + 8800000);
    // i2 (bf16) overlays h1 planes (dead after conv2lin): [0.4M, 2.8M) ✓
    unsigned short* i2 = (unsigned short*)(ws + 400000);
    int* hist_g = (int*)(ws + 23500000);         // 115,020
    int* btot = (int*)(ws + 23615020);           // 325
    int* bbase = (int*)(ws + 23615344);          // 325
    int* offs = (int*)(ws + 23665632);           // 165,626
    int* csrc = (int*)(ws + 23831264);           // 1,450,000
    float* cval = ws + 25281392;                 // 400,000
    unsigned short* c2hi = (unsigned short*)(ws + 25681392); // 98,304 ushort
    unsigned short* c2lo = c2hi + 98304;
    unsigned short* lnhi = c2lo + 98304;                     // 36,864 ushort
    unsigned short* lnlo = lnhi + 36864;
    float* decWt = ws + 25681392 + 135168;       // 18,432 floats; ends ~25,834,992 (~103.3 MB)

    conv_weights<<<(153600 + 255) / 256, 256, 0, stream>>>(
        c2Wrel, c2Wroot, linW, dW0, c2hi, c2lo, lnhi, lnlo, decWt, btot);

    // ---- binned CSR build ----
    bin_hist<<<NBLK, 256, 0, stream>>>(ei0, ei1, ei2, A1r, A2r, hist_g, btot);
    hist_scan<<<NBUCK, 64, 0, stream>>>(hist_g, btot, bbase);
    bin_scatter<<<NBLK, 256, 0, stream>>>(ei0, ei1, ei2, A1r, A1c, A1v,
                                          A2r, A2c, A2v, hist_g, bpacked, bval);
    bucket_fill<<<NBUCK, 256, 0, stream>>>(bpacked, bval, bbase, offs, csrc, cval);

    // ---- encoder ----
    conv1_b<<<1027, 256, 0, stream>>>(offs, csrc, x0, x1, x2,
                                      c1Wrel, c1Wroot, c1brel, h1hi, h1lo);
    gatherH_b<<<((size_t)NT * 16 + 255) / 256, 256, 0, stream>>>(h1hi, offs, csrc, aggh);
    conv2lin<<<1027, 256, 0, stream>>>(aggh, h1hi, h1lo, c2hi, c2lo, c2brel,
                                       lnhi, lnlo, linb, ecat16);

    // ---- interpolation (bf16 in/out; i1 over aggh, i2 over h1 planes — dead) ----
    interp_b<<<((size_t)2 * N0 * 24 + 255) / 256, 256, 0, stream>>>(
        ecat16, offs, csrc, cval, i1, i2);

    // ---- decoder ----
    dim3 gd(782, 3);
    decoder_mfma<<<gd, 256, 0, stream>>>(ecat16, i1, i2, decWt, db0, dWout, dbout, out, N0);
}